// Round 1
// baseline (1883.766 us; speedup 1.0000x reference)
//
#include <hip/hip_runtime.h>
#include <stdint.h>

#pragma clang fp contract(off)

#define NN    300000
#define TOPK  6000u
#define KW    94
#define KPAD  6016
#define SORTN 8192
#define OUTK  300
#define NEGINF_KEY 0xFF800000u

// ---------------- workspace layout (bytes) ----------------
static constexpr size_t OFF_ROI    = 0;                                   // NN*16
static constexpr size_t OFF_KEY    = OFF_ROI + (size_t)NN * 16;           // NN*4
static constexpr size_t OFF_HIST16 = ((OFF_KEY + (size_t)NN * 4 + 255) & ~(size_t)255); // 65536*4
static constexpr size_t OFF_HIST8  = OFF_HIST16 + 65536 * 4;              // 256*4
static constexpr size_t OFF_SCAL   = OFF_HIST8 + 256 * 4;                 // 256 B scalars
static constexpr size_t ZERO_BYTES = (OFF_SCAL + 256) - OFF_HIST16;
static constexpr size_t OFF_SORT   = OFF_SCAL + 256;                      // SORTN*8
static constexpr size_t OFF_SELBOX = OFF_SORT + (size_t)SORTN * 8;        // KPAD*16
static constexpr size_t OFF_SELKEY = OFF_SELBOX + (size_t)KPAD * 16;      // KPAD*4
static constexpr size_t OFF_MASK   = ((OFF_SELKEY + (size_t)KPAD * 4 + 255) & ~(size_t)255); // KPAD*KW*8
// total ~ 11 MB

// scal[] layout: [0]=P16 bin, [1]=count_below16, [2]=T24 prefix, [3]=compact counter

__device__ __forceinline__ uint32_t score_key(float s) {
  uint32_t u = __float_as_uint(s);
  u = (u >> 31) ? ~u : (u | 0x80000000u);  // monotonic: ascending uint == ascending float
  return ~u;                               // invert: ascending uint == DESCENDING float
}

// ---------------- 1. decode + key + 16-bit histogram ----------------
__global__ void k_decode(const float* __restrict__ cls, const float* __restrict__ reg,
                         const float* __restrict__ anchor, float4* __restrict__ roi,
                         uint32_t* __restrict__ key, uint32_t* __restrict__ hist16) {
  int i = blockIdx.x * blockDim.x + threadIdx.x;
  if (i >= NN) return;
  // score = softmax(cls)[1], replicated op-for-op; exp in f64 (~correctly rounded) then f32 ops
  float c0 = cls[2 * i], c1 = cls[2 * i + 1];
  float m  = fmaxf(c0, c1);
  float e0 = (float)exp((double)(c0 - m));
  float e1 = (float)exp((double)(c1 - m));
  float s  = e1 / (e0 + e1);

  float4 a = ((const float4*)anchor)[i];
  float acx = (a.x + a.z) * 0.5f;
  float acy = (a.y + a.w) * 0.5f;
  float aw  = a.z - a.x;
  float ah  = a.w - a.y;
  float4 r = ((const float4*)reg)[i];
  float cx = r.x * aw + acx;
  float cy = r.y * ah + acy;
  float w  = (float)exp((double)r.z) * aw;
  float h  = (float)exp((double)r.w) * ah;
  float x1 = cx - w * 0.5f, y1 = cy - h * 0.5f;
  float x2 = cx + w * 0.5f, y2 = cy + h * 0.5f;
  x1 = fminf(fmaxf(x1, 0.0f), 1.0f);
  y1 = fminf(fmaxf(y1, 0.0f), 1.0f);
  x2 = fminf(fmaxf(x2, 0.0f), 1.0f);
  y2 = fminf(fmaxf(y2, 0.0f), 1.0f);
  float ws_ = x2 - x1, hs_ = y2 - y1;
  bool valid = (hs_ >= 0.001f) && (ws_ >= 0.001f);
  float msc = valid ? s : -__builtin_inff();
  uint32_t kk = score_key(msc);

  roi[i] = make_float4(x1, y1, x2, y2);
  key[i] = kk;
  atomicAdd(&hist16[kk >> 16], 1u);
}

// ---------------- 2. scan 65536-bin histogram, find boundary bin ----------------
__global__ void __launch_bounds__(1024) k_scan16(const uint32_t* __restrict__ hist16,
                                                 int* __restrict__ scal) {
  __shared__ uint32_t part[1024];
  int t = threadIdx.x;
  uint32_t sum = 0;
  for (int b = 0; b < 64; b++) sum += hist16[t * 64 + b];
  part[t] = sum;
  __syncthreads();
  for (int off = 1; off < 1024; off <<= 1) {
    uint32_t v = (t >= off) ? part[t - off] : 0;
    __syncthreads();
    part[t] += v;
    __syncthreads();
  }
  uint32_t excl = part[t] - sum;
  if (excl < TOPK && excl + sum >= TOPK) {
    uint32_t cum = excl;
    for (int b = 0; b < 64; b++) {
      uint32_t h = hist16[t * 64 + b];
      if (cum < TOPK && cum + h >= TOPK) { scal[0] = t * 64 + b; scal[1] = (int)cum; break; }
      cum += h;
    }
  }
}

// ---------------- 3. 8-bit refinement histogram ----------------
__global__ void k_hist8(const uint32_t* __restrict__ key, const int* __restrict__ scal,
                        uint32_t* __restrict__ hist8) {
  int i = blockIdx.x * blockDim.x + threadIdx.x;
  if (i >= NN) return;
  uint32_t P = (uint32_t)scal[0];
  uint32_t kk = key[i];
  if ((kk >> 16) == P) atomicAdd(&hist8[(kk >> 8) & 0xFFu], 1u);
}

__global__ void __launch_bounds__(256) k_scan8(const uint32_t* __restrict__ hist8,
                                               int* __restrict__ scal) {
  __shared__ uint32_t part[256];
  int t = threadIdx.x;
  uint32_t h = hist8[t];
  part[t] = h;
  __syncthreads();
  for (int off = 1; off < 256; off <<= 1) {
    uint32_t v = (t >= off) ? part[t - off] : 0;
    __syncthreads();
    part[t] += v;
    __syncthreads();
  }
  uint32_t excl = part[t] - h;
  uint32_t cb = (uint32_t)scal[1];
  if (cb + excl < TOPK && cb + excl + h >= TOPK)
    scal[2] = (scal[0] << 8) | t;  // 24-bit prefix of the 6000th key
}

// ---------------- 4. compact candidates (prefix24 <= T24) ----------------
__global__ void k_compact(const uint32_t* __restrict__ key, int* __restrict__ scal,
                          unsigned long long* __restrict__ sortbuf) {
  int i = blockIdx.x * blockDim.x + threadIdx.x;
  if (i >= NN) return;
  uint32_t T24 = (uint32_t)scal[2];
  uint32_t kk = key[i];
  if ((kk >> 8) <= T24) {
    int pos = atomicAdd(&scal[3], 1);
    if (pos < SORTN) sortbuf[pos] = (((unsigned long long)kk) << 32) | (uint32_t)i;
  }
}

// ---------------- 5. bitonic sort 8192 u64 in LDS + gather top-6000 boxes ----------------
__global__ void __launch_bounds__(1024) k_sort(const unsigned long long* __restrict__ sortbuf,
                                               const float4* __restrict__ roi,
                                               float4* __restrict__ selbox,
                                               uint32_t* __restrict__ selkey) {
  __shared__ unsigned long long sm[SORTN];
  int t = threadIdx.x;
  for (int i = t; i < SORTN; i += 1024) sm[i] = sortbuf[i];
  __syncthreads();
  for (int k = 2; k <= SORTN; k <<= 1) {
    for (int j = k >> 1; j > 0; j >>= 1) {
      for (int p = t; p < SORTN / 2; p += 1024) {
        int i1 = ((p & ~(j - 1)) << 1) | (p & (j - 1));
        int i2 = i1 | j;
        bool up = ((i1 & k) == 0);
        unsigned long long a = sm[i1], b = sm[i2];
        if ((a > b) == up) { sm[i1] = b; sm[i2] = a; }
      }
      __syncthreads();
    }
  }
  for (int r = t; r < KPAD; r += 1024) {
    if (r < (int)TOPK) {
      unsigned long long e = sm[r];
      uint32_t idx = (uint32_t)e;
      selkey[r] = (uint32_t)(e >> 32);
      selbox[r] = roi[idx];
    } else {
      selkey[r] = NEGINF_KEY;
      selbox[r] = make_float4(0.f, 0.f, 0.f, 0.f);
    }
  }
}

// ---------------- 6. suppression bitmask matrix ----------------
__global__ void __launch_bounds__(64) k_mask(const float4* __restrict__ selbox,
                                             unsigned long long* __restrict__ mask) {
  int bi = blockIdx.x, bj = blockIdx.y;
  if (bj < bi) return;
  int t = threadIdx.x;
  __shared__ float4 jb[64];
  __shared__ float  ja[64];
  int j0 = bj * 64;
  float4 cb = selbox[j0 + t];
  jb[t] = cb;
  ja[t] = (cb.z - cb.x) * (cb.w - cb.y);
  __syncthreads();
  int i = bi * 64 + t;
  unsigned long long word = 0;
  if (i < (int)TOPK) {
    float4 bi4 = selbox[i];
    float ai = (bi4.z - bi4.x) * (bi4.w - bi4.y);
    for (int jj = 0; jj < 64; jj++) {
      int j = j0 + jj;
      float4 bb = jb[jj];
      float ltx = fmaxf(bi4.x, bb.x), lty = fmaxf(bi4.y, bb.y);
      float rbx = fminf(bi4.z, bb.z), rby = fminf(bi4.w, bb.w);
      float wx = fmaxf(rbx - ltx, 0.0f), wy = fmaxf(rby - lty, 0.0f);
      float inter = wx * wy;
      float iou = inter / (ai + ja[jj] - inter + 1e-9f);
      if (iou > 0.7f && j > i && j < (int)TOPK) word |= (1ull << jj);
    }
  }
  mask[(size_t)i * KW + bj] = word;
}

// ---------------- 7. sequential greedy keep + output ----------------
__global__ void __launch_bounds__(128) k_seq(const unsigned long long* __restrict__ mask,
                                             const uint32_t* __restrict__ selkey,
                                             const float4* __restrict__ selbox,
                                             float* __restrict__ out) {
  __shared__ unsigned long long keepw[KW];
  __shared__ uint32_t wrank[KW];
  const int t = threadIdx.x;
  if (t < KW) {
    unsigned long long w = 0;
    for (int b = 0; b < 64; b++) {
      int r = t * 64 + b;
      if (r < (int)TOPK && selkey[r] != NEGINF_KEY) w |= (1ull << b);
    }
    keepw[t] = w;
  }
  __syncthreads();
  for (int c = 0; c < KW; c++) {
    // resolve intra-chunk suppression (wave 0; uniform scalar walk over kept bits)
    if (t < 64) {
      unsigned long long mb = mask[(size_t)(c * 64 + t) * KW + c];
      unsigned long long w = keepw[c];
      unsigned long long rem = w;
      while (rem) {
        int b = (int)__builtin_ctzll(rem);
        unsigned long long mlo = __builtin_amdgcn_readlane((uint32_t)mb, b);
        unsigned long long mhi = __builtin_amdgcn_readlane((uint32_t)(mb >> 32), b);
        w &= ~((mhi << 32) | mlo);
        rem = (b >= 63) ? 0ull : (w & (~0ull << (b + 1)));
      }
      if (t == 0) keepw[c] = w;
    }
    __syncthreads();
    // kept rows of chunk c suppress all later words in parallel
    {
      unsigned long long w = keepw[c];
      int idx = c + 1 + t;
      if (idx < KW) {
        unsigned long long acc = 0;
        unsigned long long rem = w;
        while (rem) {
          int b = (int)__builtin_ctzll(rem);
          rem &= rem - 1;
          acc |= mask[(size_t)(c * 64 + b) * KW + idx];
        }
        keepw[idx] &= ~acc;
      }
    }
    __syncthreads();
  }
  // ranks of kept rows
  if (t == 0) {
    uint32_t cum = 0;
    for (int w = 0; w < KW; w++) { wrank[w] = cum; cum += (uint32_t)__popcll(keepw[w]); }
  }
  __syncthreads();
  for (int o = t; o < OUTK * 4; o += 128) out[o] = 0.0f;
  __syncthreads();
  for (int r = t; r < (int)TOPK; r += 128) {
    unsigned long long w = keepw[r >> 6];
    int b = r & 63;
    if ((w >> b) & 1ull) {
      uint32_t rank = wrank[r >> 6] + (uint32_t)__popcll(w & ((1ull << b) - 1ull));
      if (rank < OUTK) {
        float4 bx = selbox[r];
        out[rank * 4 + 0] = bx.x;
        out[rank * 4 + 1] = bx.y;
        out[rank * 4 + 2] = bx.z;
        out[rank * 4 + 3] = bx.w;
      }
    }
  }
}

// ---------------- launch ----------------
extern "C" void kernel_launch(void* const* d_in, const int* in_sizes, int n_in,
                              void* d_out, int out_size, void* d_ws, size_t ws_size,
                              hipStream_t stream) {
  const float* cls    = (const float*)d_in[0];
  const float* reg    = (const float*)d_in[1];
  const float* anchor = (const float*)d_in[2];
  float* out = (float*)d_out;
  char* ws = (char*)d_ws;

  float4*   roi     = (float4*)(ws + OFF_ROI);
  uint32_t* key     = (uint32_t*)(ws + OFF_KEY);
  uint32_t* hist16  = (uint32_t*)(ws + OFF_HIST16);
  uint32_t* hist8   = (uint32_t*)(ws + OFF_HIST8);
  int*      scal    = (int*)(ws + OFF_SCAL);
  unsigned long long* sortbuf = (unsigned long long*)(ws + OFF_SORT);
  float4*   selbox  = (float4*)(ws + OFF_SELBOX);
  uint32_t* selkey  = (uint32_t*)(ws + OFF_SELKEY);
  unsigned long long* mask = (unsigned long long*)(ws + OFF_MASK);

  hipMemsetAsync(ws + OFF_HIST16, 0, ZERO_BYTES, stream);
  hipMemsetAsync(ws + OFF_SORT, 0xFF, (size_t)SORTN * 8, stream);

  int blocks = (NN + 255) / 256;
  k_decode<<<blocks, 256, 0, stream>>>(cls, reg, anchor, roi, key, hist16);
  k_scan16<<<1, 1024, 0, stream>>>(hist16, scal);
  k_hist8<<<blocks, 256, 0, stream>>>(key, scal, hist8);
  k_scan8<<<1, 256, 0, stream>>>(hist8, scal);
  k_compact<<<blocks, 256, 0, stream>>>(key, scal, sortbuf);
  k_sort<<<1, 1024, 0, stream>>>(sortbuf, roi, selbox, selkey);
  k_mask<<<dim3(KW, KW), 64, 0, stream>>>(selbox, mask);
  k_seq<<<1, 128, 0, stream>>>(mask, selkey, selbox, out);
}

// Round 2
// 732.538 us; speedup vs baseline: 2.5716x; 2.5716x over previous
//
#include <hip/hip_runtime.h>
#include <stdint.h>

#pragma clang fp contract(off)

#define NN    300000
#define TOPK  6000u
#define KW    94
#define KPAD  6016
#define SORTN 8192
#define OUTK  300
#define NEGINF_KEY 0xFF800000u

// ---------------- workspace layout (bytes) ----------------
static constexpr size_t OFF_ROI    = 0;                                   // NN*16
static constexpr size_t OFF_KEY    = OFF_ROI + (size_t)NN * 16;           // NN*4
static constexpr size_t OFF_HIST16 = ((OFF_KEY + (size_t)NN * 4 + 255) & ~(size_t)255); // 65536*4
static constexpr size_t OFF_HIST8  = OFF_HIST16 + 65536 * 4;              // 256*4
static constexpr size_t OFF_SCAL   = OFF_HIST8 + 256 * 4;                 // 256 B scalars
static constexpr size_t ZERO_BYTES = (OFF_SCAL + 256) - OFF_HIST16;
static constexpr size_t OFF_SORT   = OFF_SCAL + 256;                      // SORTN*8
static constexpr size_t OFF_SELBOX = OFF_SORT + (size_t)SORTN * 8;        // KPAD*16
static constexpr size_t OFF_SELKEY = OFF_SELBOX + (size_t)KPAD * 16;      // KPAD*4
static constexpr size_t OFF_MASK   = ((OFF_SELKEY + (size_t)KPAD * 4 + 255) & ~(size_t)255); // KPAD*KW*8

// scal[] layout: [0]=P16 bin, [1]=count_below16, [2]=T24 prefix, [3]=compact counter

__device__ __forceinline__ uint32_t score_key(float s) {
  uint32_t u = __float_as_uint(s);
  u = (u >> 31) ? ~u : (u | 0x80000000u);  // monotonic: ascending uint == ascending float
  return ~u;                               // invert: ascending uint == DESCENDING float
}

// ---------------- 1. decode + key + 16-bit histogram ----------------
__global__ void k_decode(const float* __restrict__ cls, const float* __restrict__ reg,
                         const float* __restrict__ anchor, float4* __restrict__ roi,
                         uint32_t* __restrict__ key, uint32_t* __restrict__ hist16) {
  int i = blockIdx.x * blockDim.x + threadIdx.x;
  if (i >= NN) return;
  float c0 = cls[2 * i], c1 = cls[2 * i + 1];
  float m  = fmaxf(c0, c1);
  float e0 = (float)exp((double)(c0 - m));
  float e1 = (float)exp((double)(c1 - m));
  float s  = e1 / (e0 + e1);

  float4 a = ((const float4*)anchor)[i];
  float acx = (a.x + a.z) * 0.5f;
  float acy = (a.y + a.w) * 0.5f;
  float aw  = a.z - a.x;
  float ah  = a.w - a.y;
  float4 r = ((const float4*)reg)[i];
  float cx = r.x * aw + acx;
  float cy = r.y * ah + acy;
  float w  = (float)exp((double)r.z) * aw;
  float h  = (float)exp((double)r.w) * ah;
  float x1 = cx - w * 0.5f, y1 = cy - h * 0.5f;
  float x2 = cx + w * 0.5f, y2 = cy + h * 0.5f;
  x1 = fminf(fmaxf(x1, 0.0f), 1.0f);
  y1 = fminf(fmaxf(y1, 0.0f), 1.0f);
  x2 = fminf(fmaxf(x2, 0.0f), 1.0f);
  y2 = fminf(fmaxf(y2, 0.0f), 1.0f);
  float ws_ = x2 - x1, hs_ = y2 - y1;
  bool valid = (hs_ >= 0.001f) && (ws_ >= 0.001f);
  float msc = valid ? s : -__builtin_inff();
  uint32_t kk = score_key(msc);

  roi[i] = make_float4(x1, y1, x2, y2);
  key[i] = kk;
  atomicAdd(&hist16[kk >> 16], 1u);
}

// ---------------- 2. scan 65536-bin histogram, find boundary bin ----------------
__global__ void __launch_bounds__(1024) k_scan16(const uint32_t* __restrict__ hist16,
                                                 int* __restrict__ scal) {
  __shared__ uint32_t part[1024];
  int t = threadIdx.x;
  uint32_t sum = 0;
  for (int b = 0; b < 64; b++) sum += hist16[t * 64 + b];
  part[t] = sum;
  __syncthreads();
  for (int off = 1; off < 1024; off <<= 1) {
    uint32_t v = (t >= off) ? part[t - off] : 0;
    __syncthreads();
    part[t] += v;
    __syncthreads();
  }
  uint32_t excl = part[t] - sum;
  if (excl < TOPK && excl + sum >= TOPK) {
    uint32_t cum = excl;
    for (int b = 0; b < 64; b++) {
      uint32_t h = hist16[t * 64 + b];
      if (cum < TOPK && cum + h >= TOPK) { scal[0] = t * 64 + b; scal[1] = (int)cum; break; }
      cum += h;
    }
  }
}

// ---------------- 3. 8-bit refinement histogram ----------------
__global__ void k_hist8(const uint32_t* __restrict__ key, const int* __restrict__ scal,
                        uint32_t* __restrict__ hist8) {
  int i = blockIdx.x * blockDim.x + threadIdx.x;
  if (i >= NN) return;
  uint32_t P = (uint32_t)scal[0];
  uint32_t kk = key[i];
  if ((kk >> 16) == P) atomicAdd(&hist8[(kk >> 8) & 0xFFu], 1u);
}

__global__ void __launch_bounds__(256) k_scan8(const uint32_t* __restrict__ hist8,
                                               int* __restrict__ scal) {
  __shared__ uint32_t part[256];
  int t = threadIdx.x;
  uint32_t h = hist8[t];
  part[t] = h;
  __syncthreads();
  for (int off = 1; off < 256; off <<= 1) {
    uint32_t v = (t >= off) ? part[t - off] : 0;
    __syncthreads();
    part[t] += v;
    __syncthreads();
  }
  uint32_t excl = part[t] - h;
  uint32_t cb = (uint32_t)scal[1];
  if (cb + excl < TOPK && cb + excl + h >= TOPK)
    scal[2] = (scal[0] << 8) | t;
}

// ---------------- 4. compact candidates (prefix24 <= T24) ----------------
__global__ void k_compact(const uint32_t* __restrict__ key, int* __restrict__ scal,
                          unsigned long long* __restrict__ sortbuf) {
  int i = blockIdx.x * blockDim.x + threadIdx.x;
  if (i >= NN) return;
  uint32_t T24 = (uint32_t)scal[2];
  uint32_t kk = key[i];
  if ((kk >> 8) <= T24) {
    int pos = atomicAdd(&scal[3], 1);
    if (pos < SORTN) sortbuf[pos] = (((unsigned long long)kk) << 32) | (uint32_t)i;
  }
}

// ---------------- 5. bitonic sort 8192 u64 in LDS + gather top-6000 boxes ----------------
__global__ void __launch_bounds__(1024) k_sort(const unsigned long long* __restrict__ sortbuf,
                                               const float4* __restrict__ roi,
                                               float4* __restrict__ selbox,
                                               uint32_t* __restrict__ selkey) {
  __shared__ unsigned long long sm[SORTN];
  int t = threadIdx.x;
  for (int i = t; i < SORTN; i += 1024) sm[i] = sortbuf[i];
  __syncthreads();
  for (int k = 2; k <= SORTN; k <<= 1) {
    for (int j = k >> 1; j > 0; j >>= 1) {
      for (int p = t; p < SORTN / 2; p += 1024) {
        int i1 = ((p & ~(j - 1)) << 1) | (p & (j - 1));
        int i2 = i1 | j;
        bool up = ((i1 & k) == 0);
        unsigned long long a = sm[i1], b = sm[i2];
        if ((a > b) == up) { sm[i1] = b; sm[i2] = a; }
      }
      __syncthreads();
    }
  }
  for (int r = t; r < KPAD; r += 1024) {
    if (r < (int)TOPK) {
      unsigned long long e = sm[r];
      uint32_t idx = (uint32_t)e;
      selkey[r] = (uint32_t)(e >> 32);
      selbox[r] = roi[idx];
    } else {
      selkey[r] = NEGINF_KEY;
      selbox[r] = make_float4(0.f, 0.f, 0.f, 0.f);
    }
  }
}

// ---------------- 6. suppression bitmask matrix ----------------
__global__ void __launch_bounds__(64) k_mask(const float4* __restrict__ selbox,
                                             unsigned long long* __restrict__ mask) {
  int bi = blockIdx.x, bj = blockIdx.y;
  if (bj < bi) return;
  int t = threadIdx.x;
  __shared__ float4 jb[64];
  __shared__ float  ja[64];
  int j0 = bj * 64;
  float4 cb = selbox[j0 + t];
  jb[t] = cb;
  ja[t] = (cb.z - cb.x) * (cb.w - cb.y);
  __syncthreads();
  int i = bi * 64 + t;
  unsigned long long word = 0;
  if (i < (int)TOPK) {
    float4 bi4 = selbox[i];
    float ai = (bi4.z - bi4.x) * (bi4.w - bi4.y);
    for (int jj = 0; jj < 64; jj++) {
      int j = j0 + jj;
      float4 bb = jb[jj];
      float ltx = fmaxf(bi4.x, bb.x), lty = fmaxf(bi4.y, bb.y);
      float rbx = fminf(bi4.z, bb.z), rby = fminf(bi4.w, bb.w);
      float wx = fmaxf(rbx - ltx, 0.0f), wy = fmaxf(rby - lty, 0.0f);
      float inter = wx * wy;
      float iou = inter / (ai + ja[jj] - inter + 1e-9f);
      if (iou > 0.7f && j > i && j < (int)TOPK) word |= (1ull << jj);
    }
  }
  mask[(size_t)i * KW + bj] = word;
}

// ---------------- 7. sequential greedy keep + output ----------------
// LDS-staged, double-buffered rewrite. Per chunk c:
//   stage(c+1) issued first (hides L2/L3 latency under resolve/apply of c)
//   wave0: serial intra-chunk resolve, walking ONLY actual suppressor bits
//   barrier; parallel apply to later keep-words from LDS (word-per-thread),
//   walking only rows flagged as having a nonzero later word; barrier.
__global__ void __launch_bounds__(512) k_seq(const unsigned long long* __restrict__ mask,
                                             const uint32_t* __restrict__ selkey,
                                             const float4* __restrict__ selbox,
                                             float* __restrict__ out) {
  __shared__ unsigned long long smb[2][64][KW];   // staged rows, double-buffered (96 KB)
  __shared__ unsigned long long rowany[2][8];     // per-wave bitmask: row has nonzero word > c
  __shared__ unsigned long long keepw[KW];
  __shared__ uint32_t wrank[KW];
  const int t = threadIdx.x;
  const int lane = t & 63;
  const int wv = t >> 6;   // 8 waves

  // init keep words
  if (t < KW) {
    unsigned long long w = 0;
    for (int b = 0; b < 64; b++) {
      int r = t * 64 + b;
      if (r < (int)TOPK && selkey[r] != NEGINF_KEY) w |= (1ull << b);
    }
    keepw[t] = w;
  }

  // ---- staging helper (inlined twice): stage chunk cn into buffer p ----
  // rows r = 8k + wv handled by wave wv; words wi = cn + lane, +64
#define STAGE(cn, p)                                                          \
  {                                                                           \
    unsigned long long bits = 0;                                              \
    _Pragma("unroll")                                                         \
    for (int k = 0; k < 8; k++) {                                             \
      int r = (k << 3) + wv;                                                  \
      unsigned long long part = 0;                                            \
      for (int wi = (cn) + lane; wi < KW; wi += 64) {                         \
        unsigned long long v = mask[(size_t)((cn) * 64 + r) * KW + wi];       \
        smb[p][r][wi] = v;                                                    \
        if (wi > (cn)) part |= v;                                             \
      }                                                                       \
      if (__any(part != 0)) bits |= 1ull << ((k << 3) + wv);                  \
    }                                                                         \
    if (lane == 0) rowany[p][wv] = bits;                                      \
  }

  STAGE(0, 0)
  __syncthreads();

  for (int c = 0; c < KW; c++) {
    const int pc = c & 1;
    // issue next-chunk staging first (loads overlap with resolve/apply)
    if (c + 1 < KW) STAGE(c + 1, (c + 1) & 1)

    // phase 1: wave-0 serial resolve of chunk c (suppressor bits only)
    if (t < 64) {
      unsigned long long mb = smb[pc][lane][c];      // diag word for row lane
      unsigned long long w = keepw[c];
      unsigned long long sup = __ballot(mb != 0);
      unsigned long long rem = w & sup;
      while (rem) {
        int b = (int)__builtin_ctzll(rem);
        unsigned long long mlo = __builtin_amdgcn_readlane((uint32_t)mb, b);
        unsigned long long mhi = __builtin_amdgcn_readlane((uint32_t)(mb >> 32), b);
        w &= ~((mhi << 32) | mlo);
        rem = (b >= 63) ? 0ull : (w & sup & (~0ull << (b + 1)));
      }
      if (lane == 0) keepw[c] = w;
    }
    __syncthreads();

    // phase 2: kept suppressor rows of chunk c clear bits in later words
    {
      unsigned long long ra = rowany[pc][0] | rowany[pc][1] | rowany[pc][2] | rowany[pc][3] |
                              rowany[pc][4] | rowany[pc][5] | rowany[pc][6] | rowany[pc][7];
      unsigned long long w2 = keepw[c] & ra;
      int idx = c + 1 + t;
      if (idx < KW) {
        unsigned long long acc = 0, rem = w2;
        while (rem) {
          int b = (int)__builtin_ctzll(rem);
          rem &= rem - 1;
          acc |= smb[pc][b][idx];
        }
        keepw[idx] &= ~acc;
      }
    }
    __syncthreads();
  }
#undef STAGE

  // ranks of kept rows
  if (t == 0) {
    uint32_t cum = 0;
    for (int w = 0; w < KW; w++) { wrank[w] = cum; cum += (uint32_t)__popcll(keepw[w]); }
  }
  __syncthreads();
  for (int o = t; o < OUTK * 4; o += 512) out[o] = 0.0f;
  __syncthreads();
  for (int r = t; r < (int)TOPK; r += 512) {
    unsigned long long w = keepw[r >> 6];
    int b = r & 63;
    if ((w >> b) & 1ull) {
      uint32_t rank = wrank[r >> 6] + (uint32_t)__popcll(w & ((1ull << b) - 1ull));
      if (rank < OUTK) {
        float4 bx = selbox[r];
        out[rank * 4 + 0] = bx.x;
        out[rank * 4 + 1] = bx.y;
        out[rank * 4 + 2] = bx.z;
        out[rank * 4 + 3] = bx.w;
      }
    }
  }
}

// ---------------- launch ----------------
extern "C" void kernel_launch(void* const* d_in, const int* in_sizes, int n_in,
                              void* d_out, int out_size, void* d_ws, size_t ws_size,
                              hipStream_t stream) {
  const float* cls    = (const float*)d_in[0];
  const float* reg    = (const float*)d_in[1];
  const float* anchor = (const float*)d_in[2];
  float* out = (float*)d_out;
  char* ws = (char*)d_ws;

  float4*   roi     = (float4*)(ws + OFF_ROI);
  uint32_t* key     = (uint32_t*)(ws + OFF_KEY);
  uint32_t* hist16  = (uint32_t*)(ws + OFF_HIST16);
  uint32_t* hist8   = (uint32_t*)(ws + OFF_HIST8);
  int*      scal    = (int*)(ws + OFF_SCAL);
  unsigned long long* sortbuf = (unsigned long long*)(ws + OFF_SORT);
  float4*   selbox  = (float4*)(ws + OFF_SELBOX);
  uint32_t* selkey  = (uint32_t*)(ws + OFF_SELKEY);
  unsigned long long* mask = (unsigned long long*)(ws + OFF_MASK);

  hipMemsetAsync(ws + OFF_HIST16, 0, ZERO_BYTES, stream);
  hipMemsetAsync(ws + OFF_SORT, 0xFF, (size_t)SORTN * 8, stream);

  int blocks = (NN + 255) / 256;
  k_decode<<<blocks, 256, 0, stream>>>(cls, reg, anchor, roi, key, hist16);
  k_scan16<<<1, 1024, 0, stream>>>(hist16, scal);
  k_hist8<<<blocks, 256, 0, stream>>>(key, scal, hist8);
  k_scan8<<<1, 256, 0, stream>>>(hist8, scal);
  k_compact<<<blocks, 256, 0, stream>>>(key, scal, sortbuf);
  k_sort<<<1, 1024, 0, stream>>>(sortbuf, roi, selbox, selkey);
  k_mask<<<dim3(KW, KW), 64, 0, stream>>>(selbox, mask);
  k_seq<<<1, 512, 0, stream>>>(mask, selkey, selbox, out);
}

// Round 3
// 440.688 us; speedup vs baseline: 4.2746x; 1.6623x over previous
//
#include <hip/hip_runtime.h>
#include <stdint.h>

#pragma clang fp contract(off)

#define NN    300000
#define TOPK  6000u
#define KW    94
#define KPAD  6016
#define SORTN 8192
#define OUTK  300
#define NEGINF_KEY 0xFF800000u

// ---------------- workspace layout (bytes) ----------------
static constexpr size_t OFF_ROI    = 0;                                   // NN*16
static constexpr size_t OFF_KEY    = OFF_ROI + (size_t)NN * 16;           // NN*4
static constexpr size_t OFF_HIST16 = ((OFF_KEY + (size_t)NN * 4 + 255) & ~(size_t)255); // 65536*4
static constexpr size_t OFF_HIST8  = OFF_HIST16 + 65536 * 4;              // 256*4
static constexpr size_t OFF_SCAL   = OFF_HIST8 + 256 * 4;                 // 256 B scalars
static constexpr size_t ZERO_BYTES = (OFF_SCAL + 256) - OFF_HIST16;
static constexpr size_t OFF_SORT   = OFF_SCAL + 256;                      // SORTN*8
static constexpr size_t OFF_SELBOX = OFF_SORT + (size_t)SORTN * 8;        // KPAD*16
static constexpr size_t OFF_SELKEY = OFF_SELBOX + (size_t)KPAD * 16;      // KPAD*4
static constexpr size_t OFF_MASK   = ((OFF_SELKEY + (size_t)KPAD * 4 + 255) & ~(size_t)255); // KPAD*KW*8

// scal[] layout: [0]=P16 bin, [1]=count_below16, [2]=T24 prefix, [3]=compact counter

__device__ __forceinline__ uint32_t score_key(float s) {
  uint32_t u = __float_as_uint(s);
  u = (u >> 31) ? ~u : (u | 0x80000000u);  // monotonic: ascending uint == ascending float
  return ~u;                               // invert: ascending uint == DESCENDING float
}

// ---------------- 1. decode + key + 16-bit histogram ----------------
__global__ void k_decode(const float* __restrict__ cls, const float* __restrict__ reg,
                         const float* __restrict__ anchor, float4* __restrict__ roi,
                         uint32_t* __restrict__ key, uint32_t* __restrict__ hist16) {
  int i = blockIdx.x * blockDim.x + threadIdx.x;
  if (i >= NN) return;
  float c0 = cls[2 * i], c1 = cls[2 * i + 1];
  float m  = fmaxf(c0, c1);
  float e0 = (float)exp((double)(c0 - m));
  float e1 = (float)exp((double)(c1 - m));
  float s  = e1 / (e0 + e1);

  float4 a = ((const float4*)anchor)[i];
  float acx = (a.x + a.z) * 0.5f;
  float acy = (a.y + a.w) * 0.5f;
  float aw  = a.z - a.x;
  float ah  = a.w - a.y;
  float4 r = ((const float4*)reg)[i];
  float cx = r.x * aw + acx;
  float cy = r.y * ah + acy;
  float w  = (float)exp((double)r.z) * aw;
  float h  = (float)exp((double)r.w) * ah;
  float x1 = cx - w * 0.5f, y1 = cy - h * 0.5f;
  float x2 = cx + w * 0.5f, y2 = cy + h * 0.5f;
  x1 = fminf(fmaxf(x1, 0.0f), 1.0f);
  y1 = fminf(fmaxf(y1, 0.0f), 1.0f);
  x2 = fminf(fmaxf(x2, 0.0f), 1.0f);
  y2 = fminf(fmaxf(y2, 0.0f), 1.0f);
  float ws_ = x2 - x1, hs_ = y2 - y1;
  bool valid = (hs_ >= 0.001f) && (ws_ >= 0.001f);
  float msc = valid ? s : -__builtin_inff();
  uint32_t kk = score_key(msc);

  roi[i] = make_float4(x1, y1, x2, y2);
  key[i] = kk;
  atomicAdd(&hist16[kk >> 16], 1u);
}

// ---------------- 2. scan 65536-bin histogram, find boundary bin ----------------
__global__ void __launch_bounds__(1024) k_scan16(const uint32_t* __restrict__ hist16,
                                                 int* __restrict__ scal) {
  __shared__ uint32_t part[1024];
  int t = threadIdx.x;
  uint32_t sum = 0;
  for (int b = 0; b < 64; b++) sum += hist16[t * 64 + b];
  part[t] = sum;
  __syncthreads();
  for (int off = 1; off < 1024; off <<= 1) {
    uint32_t v = (t >= off) ? part[t - off] : 0;
    __syncthreads();
    part[t] += v;
    __syncthreads();
  }
  uint32_t excl = part[t] - sum;
  if (excl < TOPK && excl + sum >= TOPK) {
    uint32_t cum = excl;
    for (int b = 0; b < 64; b++) {
      uint32_t h = hist16[t * 64 + b];
      if (cum < TOPK && cum + h >= TOPK) { scal[0] = t * 64 + b; scal[1] = (int)cum; break; }
      cum += h;
    }
  }
}

// ---------------- 3. 8-bit refinement histogram ----------------
__global__ void k_hist8(const uint32_t* __restrict__ key, const int* __restrict__ scal,
                        uint32_t* __restrict__ hist8) {
  int i = blockIdx.x * blockDim.x + threadIdx.x;
  if (i >= NN) return;
  uint32_t P = (uint32_t)scal[0];
  uint32_t kk = key[i];
  if ((kk >> 16) == P) atomicAdd(&hist8[(kk >> 8) & 0xFFu], 1u);
}

__global__ void __launch_bounds__(256) k_scan8(const uint32_t* __restrict__ hist8,
                                               int* __restrict__ scal) {
  __shared__ uint32_t part[256];
  int t = threadIdx.x;
  uint32_t h = hist8[t];
  part[t] = h;
  __syncthreads();
  for (int off = 1; off < 256; off <<= 1) {
    uint32_t v = (t >= off) ? part[t - off] : 0;
    __syncthreads();
    part[t] += v;
    __syncthreads();
  }
  uint32_t excl = part[t] - h;
  uint32_t cb = (uint32_t)scal[1];
  if (cb + excl < TOPK && cb + excl + h >= TOPK)
    scal[2] = (scal[0] << 8) | t;
}

// ---------------- 4. compact candidates (prefix24 <= T24) ----------------
__global__ void k_compact(const uint32_t* __restrict__ key, int* __restrict__ scal,
                          unsigned long long* __restrict__ sortbuf) {
  int i = blockIdx.x * blockDim.x + threadIdx.x;
  if (i >= NN) return;
  uint32_t T24 = (uint32_t)scal[2];
  uint32_t kk = key[i];
  if ((kk >> 8) <= T24) {
    int pos = atomicAdd(&scal[3], 1);
    if (pos < SORTN) sortbuf[pos] = (((unsigned long long)kk) << 32) | (uint32_t)i;
  }
}

// ---------------- 5. bitonic sort 8192 u64 in LDS + gather top-6000 boxes ----------------
__global__ void __launch_bounds__(1024) k_sort(const unsigned long long* __restrict__ sortbuf,
                                               const float4* __restrict__ roi,
                                               float4* __restrict__ selbox,
                                               uint32_t* __restrict__ selkey) {
  __shared__ unsigned long long sm[SORTN];
  int t = threadIdx.x;
  for (int i = t; i < SORTN; i += 1024) sm[i] = sortbuf[i];
  __syncthreads();
  for (int k = 2; k <= SORTN; k <<= 1) {
    for (int j = k >> 1; j > 0; j >>= 1) {
      for (int p = t; p < SORTN / 2; p += 1024) {
        int i1 = ((p & ~(j - 1)) << 1) | (p & (j - 1));
        int i2 = i1 | j;
        bool up = ((i1 & k) == 0);
        unsigned long long a = sm[i1], b = sm[i2];
        if ((a > b) == up) { sm[i1] = b; sm[i2] = a; }
      }
      __syncthreads();
    }
  }
  for (int r = t; r < KPAD; r += 1024) {
    if (r < (int)TOPK) {
      unsigned long long e = sm[r];
      uint32_t idx = (uint32_t)e;
      selkey[r] = (uint32_t)(e >> 32);
      selbox[r] = roi[idx];
    } else {
      selkey[r] = NEGINF_KEY;
      selbox[r] = make_float4(0.f, 0.f, 0.f, 0.f);
    }
  }
}

// ---------------- 6. suppression bitmask matrix ----------------
__global__ void __launch_bounds__(64) k_mask(const float4* __restrict__ selbox,
                                             unsigned long long* __restrict__ mask) {
  int bi = blockIdx.x, bj = blockIdx.y;
  if (bj < bi) return;
  int t = threadIdx.x;
  __shared__ float4 jb[64];
  __shared__ float  ja[64];
  int j0 = bj * 64;
  float4 cb = selbox[j0 + t];
  jb[t] = cb;
  ja[t] = (cb.z - cb.x) * (cb.w - cb.y);
  __syncthreads();
  int i = bi * 64 + t;
  unsigned long long word = 0;
  if (i < (int)TOPK) {
    float4 bi4 = selbox[i];
    float ai = (bi4.z - bi4.x) * (bi4.w - bi4.y);
    for (int jj = 0; jj < 64; jj++) {
      int j = j0 + jj;
      float4 bb = jb[jj];
      float ltx = fmaxf(bi4.x, bb.x), lty = fmaxf(bi4.y, bb.y);
      float rbx = fminf(bi4.z, bb.z), rby = fminf(bi4.w, bb.w);
      float wx = fmaxf(rbx - ltx, 0.0f), wy = fmaxf(rby - lty, 0.0f);
      float inter = wx * wy;
      float iou = inter / (ai + ja[jj] - inter + 1e-9f);
      if (iou > 0.7f && j > i && j < (int)TOPK) word |= (1ull << jj);
    }
  }
  mask[(size_t)i * KW + bj] = word;
}

// ---------------- 7. sequential greedy keep + output ----------------
// Prefetch-depth-2 async-STAGE split (T14): loads for chunk c+2 issued at the
// top of chunk c into static reg sets (VA/VB, loop unrolled x2); LDS writes
// for chunk c+1 happen after phase2 (their loads landed a full chunk ago).
// Per-chunk critical path: phase1 walk + phase2 walk + 6 ds_writes + 2 barriers.
__global__ void __launch_bounds__(512) k_seq(const unsigned long long* __restrict__ mask,
                                             const uint32_t* __restrict__ selkey,
                                             const float4* __restrict__ selbox,
                                             float* __restrict__ out) {
  __shared__ unsigned long long smb[2][64][KW];   // 96256 B, double-buffered chunk rows
  __shared__ unsigned long long keepw[KW];
  __shared__ uint32_t wrank[KW];
  __shared__ uint32_t rowflag[2][64];             // row has nonzero word > chunk
  const int t = threadIdx.x;
  const int lane = t & 63;

  // static per-thread staging map: 64 rows x 47 ulonglong2 = 3008 chunks, 6 iters
  int offs[6], w0[6], rr[6];
#pragma unroll
  for (int it = 0; it < 6; it++) {
    int idx = it * 512 + t;
    int r = idx / 47, c2 = idx - r * 47;
    offs[it] = r * (KW * 8) + c2 * 16;
    w0[it] = 2 * c2;
    rr[it] = r;
  }
  ulonglong2 VA[6], VB[6];

#define STAGE_LOAD(cn, V)                                                     \
  if ((cn) < KW) {                                                            \
    const char* mb_ = (const char*)mask + (size_t)(cn) * (64 * KW * 8);       \
    _Pragma("unroll")                                                         \
    for (int it = 0; it < 6; it++)                                            \
      if (it < 5 || t < 448) V[it] = *(const ulonglong2*)(mb_ + offs[it]);    \
  }

#define STAGE_WRITE(cn, V, p)                                                 \
  if ((cn) < KW) {                                                            \
    char* sb_ = (char*)&smb[p][0][0];                                         \
    _Pragma("unroll")                                                         \
    for (int it = 0; it < 6; it++)                                            \
      if (it < 5 || t < 448) {                                                \
        *(ulonglong2*)(sb_ + offs[it]) = V[it];                               \
        unsigned long long nz =                                               \
            (w0[it] > (cn)) ? (V[it].x | V[it].y)                             \
                            : ((w0[it] + 1 > (cn)) ? V[it].y : 0ull);         \
        if (nz) atomicOr(&rowflag[p][rr[it]], 1u);                            \
      }                                                                       \
  }

  // ---- prologue: chunk 0 and 1 in flight; chunk 0 written ----
  STAGE_LOAD(0, VA)
  STAGE_LOAD(1, VB)
  if (t < 64) { rowflag[0][t] = 0; rowflag[1][t] = 0; }
  if (t < KW) {
    unsigned long long w = 0;
    for (int b = 0; b < 64; b++) {
      int r = t * 64 + b;
      if (r < (int)TOPK && selkey[r] != NEGINF_KEY) w |= (1ull << b);
    }
    keepw[t] = w;
  }
  __syncthreads();               // rowflag zero visible before STAGE_WRITE's atomicOr
  STAGE_WRITE(0, VA, 0)          // vmcnt auto-wait on VA only
  __syncthreads();

#define CHUNK_BODY(c, VL, VW)                                                 \
  {                                                                           \
    const int pc = (c) & 1, qn = ((c) + 1) & 1;                               \
    STAGE_LOAD((c) + 2, VL)                                                   \
    if (t < 64) rowflag[qn][t] = 0;                                           \
    if (t < 64) {                                                             \
      unsigned long long mb = smb[pc][lane][(c)];                             \
      unsigned long long w = keepw[(c)];                                      \
      unsigned long long sup = __ballot(mb != 0);                             \
      unsigned long long rem = w & sup;                                       \
      while (rem) {                                                           \
        int b = (int)__builtin_ctzll(rem);                                    \
        unsigned long long mlo = __builtin_amdgcn_readlane((uint32_t)mb, b);  \
        unsigned long long mhi =                                              \
            __builtin_amdgcn_readlane((uint32_t)(mb >> 32), b);               \
        w &= ~((mhi << 32) | mlo);                                            \
        rem = (b >= 63) ? 0ull : (w & sup & (~0ull << (b + 1)));              \
      }                                                                       \
      if (lane == 0) keepw[(c)] = w;                                          \
    }                                                                         \
    __syncthreads();                                                          \
    {                                                                         \
      uint32_t rfv = rowflag[pc][lane];                                       \
      unsigned long long ra = __ballot(rfv != 0);                             \
      unsigned long long w2 = keepw[(c)] & ra;                                \
      int idx = (c) + 1 + t;                                                  \
      if (idx < KW) {                                                         \
        unsigned long long acc = 0, rem2 = w2;                                \
        while (rem2) {                                                        \
          int b = (int)__builtin_ctzll(rem2);                                 \
          rem2 &= rem2 - 1;                                                   \
          acc |= smb[pc][b][idx];                                             \
        }                                                                     \
        keepw[idx] &= ~acc;                                                   \
      }                                                                       \
    }                                                                         \
    STAGE_WRITE((c) + 1, VW, qn)                                              \
    __syncthreads();                                                          \
  }

  for (int c = 0; c < KW; c += 2) {
    CHUNK_BODY(c, VA, VB)        // even: load c+2 -> VA, write c+1 from VB
    CHUNK_BODY(c + 1, VB, VA)    // odd:  load c+3 -> VB, write c+2 from VA
  }
#undef CHUNK_BODY
#undef STAGE_LOAD
#undef STAGE_WRITE

  // ranks of kept rows
  if (t == 0) {
    uint32_t cum = 0;
    for (int w = 0; w < KW; w++) { wrank[w] = cum; cum += (uint32_t)__popcll(keepw[w]); }
  }
  __syncthreads();
  for (int o = t; o < OUTK * 4; o += 512) out[o] = 0.0f;
  __syncthreads();
  for (int r = t; r < (int)TOPK; r += 512) {
    unsigned long long w = keepw[r >> 6];
    int b = r & 63;
    if ((w >> b) & 1ull) {
      uint32_t rank = wrank[r >> 6] + (uint32_t)__popcll(w & ((1ull << b) - 1ull));
      if (rank < OUTK) {
        float4 bx = selbox[r];
        out[rank * 4 + 0] = bx.x;
        out[rank * 4 + 1] = bx.y;
        out[rank * 4 + 2] = bx.z;
        out[rank * 4 + 3] = bx.w;
      }
    }
  }
}

// ---------------- launch ----------------
extern "C" void kernel_launch(void* const* d_in, const int* in_sizes, int n_in,
                              void* d_out, int out_size, void* d_ws, size_t ws_size,
                              hipStream_t stream) {
  const float* cls    = (const float*)d_in[0];
  const float* reg    = (const float*)d_in[1];
  const float* anchor = (const float*)d_in[2];
  float* out = (float*)d_out;
  char* ws = (char*)d_ws;

  float4*   roi     = (float4*)(ws + OFF_ROI);
  uint32_t* key     = (uint32_t*)(ws + OFF_KEY);
  uint32_t* hist16  = (uint32_t*)(ws + OFF_HIST16);
  uint32_t* hist8   = (uint32_t*)(ws + OFF_HIST8);
  int*      scal    = (int*)(ws + OFF_SCAL);
  unsigned long long* sortbuf = (unsigned long long*)(ws + OFF_SORT);
  float4*   selbox  = (float4*)(ws + OFF_SELBOX);
  uint32_t* selkey  = (uint32_t*)(ws + OFF_SELKEY);
  unsigned long long* mask = (unsigned long long*)(ws + OFF_MASK);

  hipMemsetAsync(ws + OFF_HIST16, 0, ZERO_BYTES, stream);
  hipMemsetAsync(ws + OFF_SORT, 0xFF, (size_t)SORTN * 8, stream);

  int blocks = (NN + 255) / 256;
  k_decode<<<blocks, 256, 0, stream>>>(cls, reg, anchor, roi, key, hist16);
  k_scan16<<<1, 1024, 0, stream>>>(hist16, scal);
  k_hist8<<<blocks, 256, 0, stream>>>(key, scal, hist8);
  k_scan8<<<1, 256, 0, stream>>>(hist8, scal);
  k_compact<<<blocks, 256, 0, stream>>>(key, scal, sortbuf);
  k_sort<<<1, 1024, 0, stream>>>(sortbuf, roi, selbox, selkey);
  k_mask<<<dim3(KW, KW), 64, 0, stream>>>(selbox, mask);
  k_seq<<<1, 512, 0, stream>>>(mask, selkey, selbox, out);
}

// Round 4
// 415.049 us; speedup vs baseline: 4.5387x; 1.0618x over previous
//
#include <hip/hip_runtime.h>
#include <stdint.h>

#pragma clang fp contract(off)

#define NN    300000
#define TOPK  6000u
#define KW    94
#define KPAD  6016
#define SORTN 8192
#define OUTK  300
#define NEGINF_KEY 0xFF800000u

// ---------------- workspace layout (bytes) ----------------
static constexpr size_t OFF_ROI    = 0;                                   // NN*16
static constexpr size_t OFF_KEY    = OFF_ROI + (size_t)NN * 16;           // NN*4
static constexpr size_t OFF_HIST16 = ((OFF_KEY + (size_t)NN * 4 + 255) & ~(size_t)255); // 65536*4
static constexpr size_t OFF_HIST8  = OFF_HIST16 + 65536 * 4;              // 256*4
static constexpr size_t OFF_SCAL   = OFF_HIST8 + 256 * 4;                 // 256 B scalars
static constexpr size_t ZERO_BYTES = (OFF_SCAL + 256) - OFF_HIST16;
static constexpr size_t OFF_SORT   = OFF_SCAL + 256;                      // SORTN*8
static constexpr size_t OFF_SELBOX = OFF_SORT + (size_t)SORTN * 8;        // KPAD*16
static constexpr size_t OFF_SELKEY = OFF_SELBOX + (size_t)KPAD * 16;      // KPAD*4
static constexpr size_t OFF_MASK   = ((OFF_SELKEY + (size_t)KPAD * 4 + 255) & ~(size_t)255); // KPAD*KW*8

// scal[] layout: [0]=P16 bin, [1]=count_below16, [2]=T24 prefix, [3]=compact counter

__device__ __forceinline__ uint32_t score_key(float s) {
  uint32_t u = __float_as_uint(s);
  u = (u >> 31) ? ~u : (u | 0x80000000u);  // monotonic: ascending uint == ascending float
  return ~u;                               // invert: ascending uint == DESCENDING float
}

// ---------------- 1. decode + key + 16-bit histogram ----------------
__global__ void k_decode(const float* __restrict__ cls, const float* __restrict__ reg,
                         const float* __restrict__ anchor, float4* __restrict__ roi,
                         uint32_t* __restrict__ key, uint32_t* __restrict__ hist16) {
  int i = blockIdx.x * blockDim.x + threadIdx.x;
  if (i >= NN) return;
  // softmax(cls)[1], bit-identical op sequence to before; exp(0)==1.0 exactly,
  // so only ONE f64 exp is needed (of the non-max argument).
  float c0 = cls[2 * i], c1 = cls[2 * i + 1];
  float m  = fmaxf(c0, c1);
  float a0 = c0 - m, a1 = c1 - m;          // one is exactly 0.0f
  float tn = fminf(a0, a1);
  float e  = (float)exp((double)tn);
  float e0 = (a0 == 0.0f) ? 1.0f : e;
  float e1 = (a1 == 0.0f) ? 1.0f : e;
  float s  = e1 / (e0 + e1);

  float4 a = ((const float4*)anchor)[i];
  float acx = (a.x + a.z) * 0.5f;
  float acy = (a.y + a.w) * 0.5f;
  float aw  = a.z - a.x;
  float ah  = a.w - a.y;
  float4 r = ((const float4*)reg)[i];
  float cx = r.x * aw + acx;
  float cy = r.y * ah + acy;
  float w  = (float)exp((double)r.z) * aw;
  float h  = (float)exp((double)r.w) * ah;
  float x1 = cx - w * 0.5f, y1 = cy - h * 0.5f;
  float x2 = cx + w * 0.5f, y2 = cy + h * 0.5f;
  x1 = fminf(fmaxf(x1, 0.0f), 1.0f);
  y1 = fminf(fmaxf(y1, 0.0f), 1.0f);
  x2 = fminf(fmaxf(x2, 0.0f), 1.0f);
  y2 = fminf(fmaxf(y2, 0.0f), 1.0f);
  float ws_ = x2 - x1, hs_ = y2 - y1;
  bool valid = (hs_ >= 0.001f) && (ws_ >= 0.001f);
  float msc = valid ? s : -__builtin_inff();
  uint32_t kk = score_key(msc);

  roi[i] = make_float4(x1, y1, x2, y2);
  key[i] = kk;
  // invalid lanes all map to ONE bin (0xFF80) -> same-address atomic serialization.
  // The scan never needs that bin (invalid keys can't reach top-6000): skip them.
  if (valid) atomicAdd(&hist16[kk >> 16], 1u);
}

// ---------------- 2. scan 65536-bin histogram, find boundary bin ----------------
__global__ void __launch_bounds__(1024) k_scan16(const uint32_t* __restrict__ hist16,
                                                 int* __restrict__ scal) {
  __shared__ uint32_t part[1024];
  int t = threadIdx.x;
  uint32_t sum = 0;
  for (int b = 0; b < 64; b++) sum += hist16[t * 64 + b];
  part[t] = sum;
  __syncthreads();
  for (int off = 1; off < 1024; off <<= 1) {
    uint32_t v = (t >= off) ? part[t - off] : 0;
    __syncthreads();
    part[t] += v;
    __syncthreads();
  }
  uint32_t excl = part[t] - sum;
  if (excl < TOPK && excl + sum >= TOPK) {
    uint32_t cum = excl;
    for (int b = 0; b < 64; b++) {
      uint32_t h = hist16[t * 64 + b];
      if (cum < TOPK && cum + h >= TOPK) { scal[0] = t * 64 + b; scal[1] = (int)cum; break; }
      cum += h;
    }
  }
}

// ---------------- 3. 8-bit refinement histogram ----------------
__global__ void k_hist8(const uint32_t* __restrict__ key, const int* __restrict__ scal,
                        uint32_t* __restrict__ hist8) {
  int i = blockIdx.x * blockDim.x + threadIdx.x;
  if (i >= NN) return;
  uint32_t P = (uint32_t)scal[0];
  uint32_t kk = key[i];
  if ((kk >> 16) == P) atomicAdd(&hist8[(kk >> 8) & 0xFFu], 1u);
}

__global__ void __launch_bounds__(256) k_scan8(const uint32_t* __restrict__ hist8,
                                               int* __restrict__ scal) {
  __shared__ uint32_t part[256];
  int t = threadIdx.x;
  uint32_t h = hist8[t];
  part[t] = h;
  __syncthreads();
  for (int off = 1; off < 256; off <<= 1) {
    uint32_t v = (t >= off) ? part[t - off] : 0;
    __syncthreads();
    part[t] += v;
    __syncthreads();
  }
  uint32_t excl = part[t] - h;
  uint32_t cb = (uint32_t)scal[1];
  if (cb + excl < TOPK && cb + excl + h >= TOPK)
    scal[2] = (scal[0] << 8) | t;
}

// ---------------- 4. compact candidates (prefix24 <= T24) ----------------
// Block-aggregated cursor: one global atomic per block instead of ~7000
// same-address per-thread atomics. Order within sortbuf is irrelevant
// (bitonic sort re-establishes the total (key,idx) order).
__global__ void k_compact(const uint32_t* __restrict__ key, int* __restrict__ scal,
                          unsigned long long* __restrict__ sortbuf) {
  __shared__ int lcnt, lbase;
  int t = threadIdx.x;
  int i = blockIdx.x * blockDim.x + t;
  if (t == 0) lcnt = 0;
  __syncthreads();
  bool sel = false;
  uint32_t kk = 0;
  int my = 0;
  if (i < NN) {
    uint32_t T24 = (uint32_t)scal[2];
    kk = key[i];
    if ((kk >> 8) <= T24) { sel = true; my = atomicAdd(&lcnt, 1); }
  }
  __syncthreads();
  if (t == 0 && lcnt > 0) lbase = atomicAdd(&scal[3], lcnt);
  __syncthreads();
  if (sel) {
    int pos = lbase + my;
    if (pos < SORTN) sortbuf[pos] = (((unsigned long long)kk) << 32) | (uint32_t)i;
  }
}

// ---------------- 5. bitonic sort 8192 u64 in LDS + gather top-6000 boxes ----------------
__global__ void __launch_bounds__(1024) k_sort(const unsigned long long* __restrict__ sortbuf,
                                               const float4* __restrict__ roi,
                                               float4* __restrict__ selbox,
                                               uint32_t* __restrict__ selkey) {
  __shared__ unsigned long long sm[SORTN];
  int t = threadIdx.x;
  for (int i = t; i < SORTN; i += 1024) sm[i] = sortbuf[i];
  __syncthreads();
  for (int k = 2; k <= SORTN; k <<= 1) {
    for (int j = k >> 1; j > 0; j >>= 1) {
      for (int p = t; p < SORTN / 2; p += 1024) {
        int i1 = ((p & ~(j - 1)) << 1) | (p & (j - 1));
        int i2 = i1 | j;
        bool up = ((i1 & k) == 0);
        unsigned long long a = sm[i1], b = sm[i2];
        if ((a > b) == up) { sm[i1] = b; sm[i2] = a; }
      }
      __syncthreads();
    }
  }
  for (int r = t; r < KPAD; r += 1024) {
    if (r < (int)TOPK) {
      unsigned long long e = sm[r];
      uint32_t idx = (uint32_t)e;
      selkey[r] = (uint32_t)(e >> 32);
      selbox[r] = roi[idx];
    } else {
      selkey[r] = NEGINF_KEY;
      selbox[r] = make_float4(0.f, 0.f, 0.f, 0.f);
    }
  }
}

// ---------------- 6. suppression bitmask matrix ----------------
__global__ void __launch_bounds__(64) k_mask(const float4* __restrict__ selbox,
                                             unsigned long long* __restrict__ mask) {
  int bi = blockIdx.x, bj = blockIdx.y;
  if (bj < bi) return;
  int t = threadIdx.x;
  __shared__ float4 jb[64];
  __shared__ float  ja[64];
  int j0 = bj * 64;
  float4 cb = selbox[j0 + t];
  jb[t] = cb;
  ja[t] = (cb.z - cb.x) * (cb.w - cb.y);
  __syncthreads();
  int i = bi * 64 + t;
  unsigned long long word = 0;
  if (i < (int)TOPK) {
    float4 bi4 = selbox[i];
    float ai = (bi4.z - bi4.x) * (bi4.w - bi4.y);
    for (int jj = 0; jj < 64; jj++) {
      int j = j0 + jj;
      float4 bb = jb[jj];
      float ltx = fmaxf(bi4.x, bb.x), lty = fmaxf(bi4.y, bb.y);
      float rbx = fminf(bi4.z, bb.z), rby = fminf(bi4.w, bb.w);
      float wx = fmaxf(rbx - ltx, 0.0f), wy = fmaxf(rby - lty, 0.0f);
      float inter = wx * wy;
      float iou = inter / (ai + ja[jj] - inter + 1e-9f);
      if (iou > 0.7f && j > i && j < (int)TOPK) word |= (1ull << jj);
    }
  }
  mask[(size_t)i * KW + bj] = word;
}

// ---------------- 7. sequential greedy keep + output ----------------
__global__ void __launch_bounds__(512) k_seq(const unsigned long long* __restrict__ mask,
                                             const uint32_t* __restrict__ selkey,
                                             const float4* __restrict__ selbox,
                                             float* __restrict__ out) {
  __shared__ unsigned long long smb[2][64][KW];   // 96256 B, double-buffered chunk rows
  __shared__ unsigned long long keepw[KW];
  __shared__ uint32_t wrank[KW];
  __shared__ uint32_t rowflag[2][64];             // row has nonzero word > chunk
  const int t = threadIdx.x;
  const int lane = t & 63;

  // static per-thread staging map: 64 rows x 47 ulonglong2 = 3008 chunks, 6 iters
  int offs[6], w0[6], rr[6];
#pragma unroll
  for (int it = 0; it < 6; it++) {
    int idx = it * 512 + t;
    int r = idx / 47, c2 = idx - r * 47;
    offs[it] = r * (KW * 8) + c2 * 16;
    w0[it] = 2 * c2;
    rr[it] = r;
  }
  ulonglong2 VA[6], VB[6];

#define STAGE_LOAD(cn, V)                                                     \
  if ((cn) < KW) {                                                            \
    const char* mb_ = (const char*)mask + (size_t)(cn) * (64 * KW * 8);       \
    _Pragma("unroll")                                                         \
    for (int it = 0; it < 6; it++)                                            \
      if (it < 5 || t < 448) V[it] = *(const ulonglong2*)(mb_ + offs[it]);    \
  }

#define STAGE_WRITE(cn, V, p)                                                 \
  if ((cn) < KW) {                                                            \
    char* sb_ = (char*)&smb[p][0][0];                                         \
    _Pragma("unroll")                                                         \
    for (int it = 0; it < 6; it++)                                            \
      if (it < 5 || t < 448) {                                                \
        *(ulonglong2*)(sb_ + offs[it]) = V[it];                               \
        unsigned long long nz =                                               \
            (w0[it] > (cn)) ? (V[it].x | V[it].y)                             \
                            : ((w0[it] + 1 > (cn)) ? V[it].y : 0ull);         \
        if (nz) atomicOr(&rowflag[p][rr[it]], 1u);                            \
      }                                                                       \
  }

  // ---- prologue: chunk 0 and 1 in flight; chunk 0 written ----
  STAGE_LOAD(0, VA)
  STAGE_LOAD(1, VB)
  if (t < 64) { rowflag[0][t] = 0; rowflag[1][t] = 0; }
  if (t < KW) {
    unsigned long long w = 0;
    for (int b = 0; b < 64; b++) {
      int r = t * 64 + b;
      if (r < (int)TOPK && selkey[r] != NEGINF_KEY) w |= (1ull << b);
    }
    keepw[t] = w;
  }
  __syncthreads();               // rowflag zero visible before STAGE_WRITE's atomicOr
  STAGE_WRITE(0, VA, 0)          // vmcnt auto-wait on VA only
  __syncthreads();

#define CHUNK_BODY(c, VL, VW)                                                 \
  {                                                                           \
    const int pc = (c) & 1, qn = ((c) + 1) & 1;                               \
    STAGE_LOAD((c) + 2, VL)                                                   \
    if (t < 64) rowflag[qn][t] = 0;                                           \
    if (t < 64) {                                                             \
      unsigned long long mb = smb[pc][lane][(c)];                             \
      unsigned long long w = keepw[(c)];                                      \
      unsigned long long sup = __ballot(mb != 0);                             \
      unsigned long long rem = w & sup;                                       \
      while (rem) {                                                           \
        int b = (int)__builtin_ctzll(rem);                                    \
        unsigned long long mlo = __builtin_amdgcn_readlane((uint32_t)mb, b);  \
        unsigned long long mhi =                                              \
            __builtin_amdgcn_readlane((uint32_t)(mb >> 32), b);               \
        w &= ~((mhi << 32) | mlo);                                            \
        rem = (b >= 63) ? 0ull : (w & sup & (~0ull << (b + 1)));              \
      }                                                                       \
      if (lane == 0) keepw[(c)] = w;                                          \
    }                                                                         \
    __syncthreads();                                                          \
    {                                                                         \
      uint32_t rfv = rowflag[pc][lane];                                       \
      unsigned long long ra = __ballot(rfv != 0);                             \
      unsigned long long w2 = keepw[(c)] & ra;                                \
      int idx = (c) + 1 + t;                                                  \
      if (idx < KW) {                                                         \
        unsigned long long acc = 0, rem2 = w2;                                \
        while (rem2) {                                                        \
          int b = (int)__builtin_ctzll(rem2);                                 \
          rem2 &= rem2 - 1;                                                   \
          acc |= smb[pc][b][idx];                                             \
        }                                                                     \
        keepw[idx] &= ~acc;                                                   \
      }                                                                       \
    }                                                                         \
    STAGE_WRITE((c) + 1, VW, qn)                                              \
    __syncthreads();                                                          \
  }

  for (int c = 0; c < KW; c += 2) {
    CHUNK_BODY(c, VA, VB)        // even: load c+2 -> VA, write c+1 from VB
    CHUNK_BODY(c + 1, VB, VA)    // odd:  load c+3 -> VB, write c+2 from VA
  }
#undef CHUNK_BODY
#undef STAGE_LOAD
#undef STAGE_WRITE

  // ranks of kept rows
  if (t == 0) {
    uint32_t cum = 0;
    for (int w = 0; w < KW; w++) { wrank[w] = cum; cum += (uint32_t)__popcll(keepw[w]); }
  }
  __syncthreads();
  for (int o = t; o < OUTK * 4; o += 512) out[o] = 0.0f;
  __syncthreads();
  for (int r = t; r < (int)TOPK; r += 512) {
    unsigned long long w = keepw[r >> 6];
    int b = r & 63;
    if ((w >> b) & 1ull) {
      uint32_t rank = wrank[r >> 6] + (uint32_t)__popcll(w & ((1ull << b) - 1ull));
      if (rank < OUTK) {
        float4 bx = selbox[r];
        out[rank * 4 + 0] = bx.x;
        out[rank * 4 + 1] = bx.y;
        out[rank * 4 + 2] = bx.z;
        out[rank * 4 + 3] = bx.w;
      }
    }
  }
}

// ---------------- launch ----------------
extern "C" void kernel_launch(void* const* d_in, const int* in_sizes, int n_in,
                              void* d_out, int out_size, void* d_ws, size_t ws_size,
                              hipStream_t stream) {
  const float* cls    = (const float*)d_in[0];
  const float* reg    = (const float*)d_in[1];
  const float* anchor = (const float*)d_in[2];
  float* out = (float*)d_out;
  char* ws = (char*)d_ws;

  float4*   roi     = (float4*)(ws + OFF_ROI);
  uint32_t* key     = (uint32_t*)(ws + OFF_KEY);
  uint32_t* hist16  = (uint32_t*)(ws + OFF_HIST16);
  uint32_t* hist8   = (uint32_t*)(ws + OFF_HIST8);
  int*      scal    = (int*)(ws + OFF_SCAL);
  unsigned long long* sortbuf = (unsigned long long*)(ws + OFF_SORT);
  float4*   selbox  = (float4*)(ws + OFF_SELBOX);
  uint32_t* selkey  = (uint32_t*)(ws + OFF_SELKEY);
  unsigned long long* mask = (unsigned long long*)(ws + OFF_MASK);

  hipMemsetAsync(ws + OFF_HIST16, 0, ZERO_BYTES, stream);
  hipMemsetAsync(ws + OFF_SORT, 0xFF, (size_t)SORTN * 8, stream);

  int blocks = (NN + 255) / 256;
  k_decode<<<blocks, 256, 0, stream>>>(cls, reg, anchor, roi, key, hist16);
  k_scan16<<<1, 1024, 0, stream>>>(hist16, scal);
  k_hist8<<<blocks, 256, 0, stream>>>(key, scal, hist8);
  k_scan8<<<1, 256, 0, stream>>>(hist8, scal);
  k_compact<<<blocks, 256, 0, stream>>>(key, scal, sortbuf);
  k_sort<<<1, 1024, 0, stream>>>(sortbuf, roi, selbox, selkey);
  k_mask<<<dim3(KW, KW), 64, 0, stream>>>(selbox, mask);
  k_seq<<<1, 512, 0, stream>>>(mask, selkey, selbox, out);
}

// Round 5
// 306.887 us; speedup vs baseline: 6.1383x; 1.3525x over previous
//
#include <hip/hip_runtime.h>
#include <stdint.h>

#pragma clang fp contract(off)

#define NN    300000
#define TOPK  6000u
#define KW    94
#define KPAD  6016
#define SORTN 8192
#define OUTK  300
#define NEGINF_KEY 0xFF800000u

// ---------------- workspace layout (bytes) ----------------
static constexpr size_t OFF_ROI    = 0;                                   // NN*16
static constexpr size_t OFF_KEY    = OFF_ROI + (size_t)NN * 16;           // NN*4
static constexpr size_t OFF_HIST16 = ((OFF_KEY + (size_t)NN * 4 + 255) & ~(size_t)255); // 65536*4
static constexpr size_t OFF_HIST8  = OFF_HIST16 + 65536 * 4;              // 256*4
static constexpr size_t OFF_SCAL   = OFF_HIST8 + 256 * 4;                 // 256 B scalars
static constexpr size_t ZERO_BYTES = (OFF_SCAL + 256) - OFF_HIST16;
static constexpr size_t OFF_SORT   = OFF_SCAL + 256;                      // SORTN*8
static constexpr size_t OFF_SELBOX = OFF_SORT + (size_t)SORTN * 8;        // KPAD*16
static constexpr size_t OFF_SELKEY = OFF_SELBOX + (size_t)KPAD * 16;      // KPAD*4
static constexpr size_t OFF_MASK   = ((OFF_SELKEY + (size_t)KPAD * 4 + 255) & ~(size_t)255); // KPAD*KW*8

// scal[] layout: [0]=P16 bin, [1]=count_below16, [2]=T24 prefix, [3]=compact counter

__device__ __forceinline__ uint32_t score_key(float s) {
  uint32_t u = __float_as_uint(s);
  u = (u >> 31) ? ~u : (u | 0x80000000u);  // monotonic: ascending uint == ascending float
  return ~u;                               // invert: ascending uint == DESCENDING float
}

// bit-reversed histogram slot: consecutive bins -> distinct cache lines.
// (bins sharing a 64B line differ only in original bits [15:12])
__device__ __forceinline__ uint32_t hslot(uint32_t b) { return __brev(b) >> 16; }

// ---------------- 1. decode + key + 16-bit histogram ----------------
__global__ void k_decode(const float* __restrict__ cls, const float* __restrict__ reg,
                         const float* __restrict__ anchor, float4* __restrict__ roi,
                         uint32_t* __restrict__ key, uint32_t* __restrict__ hist16) {
  int i = blockIdx.x * blockDim.x + threadIdx.x;
  if (i >= NN) return;
  // softmax(cls)[1], bit-identical op sequence; exp(0)==1.0 exactly -> one f64 exp
  float c0 = cls[2 * i], c1 = cls[2 * i + 1];
  float m  = fmaxf(c0, c1);
  float a0 = c0 - m, a1 = c1 - m;          // one is exactly 0.0f
  float tn = fminf(a0, a1);
  float e  = (float)exp((double)tn);
  float e0 = (a0 == 0.0f) ? 1.0f : e;
  float e1 = (a1 == 0.0f) ? 1.0f : e;
  float s  = e1 / (e0 + e1);

  float4 a = ((const float4*)anchor)[i];
  float acx = (a.x + a.z) * 0.5f;
  float acy = (a.y + a.w) * 0.5f;
  float aw  = a.z - a.x;
  float ah  = a.w - a.y;
  float4 r = ((const float4*)reg)[i];
  float cx = r.x * aw + acx;
  float cy = r.y * ah + acy;
  float w  = (float)exp((double)r.z) * aw;
  float h  = (float)exp((double)r.w) * ah;
  float x1 = cx - w * 0.5f, y1 = cy - h * 0.5f;
  float x2 = cx + w * 0.5f, y2 = cy + h * 0.5f;
  x1 = fminf(fmaxf(x1, 0.0f), 1.0f);
  y1 = fminf(fmaxf(y1, 0.0f), 1.0f);
  x2 = fminf(fmaxf(x2, 0.0f), 1.0f);
  y2 = fminf(fmaxf(y2, 0.0f), 1.0f);
  float ws_ = x2 - x1, hs_ = y2 - y1;
  bool valid = (hs_ >= 0.001f) && (ws_ >= 0.001f);
  float msc = valid ? s : -__builtin_inff();
  uint32_t kk = score_key(msc);

  roi[i] = make_float4(x1, y1, x2, y2);
  key[i] = kk;
  // bit-reversed slot spreads the hot score octaves (128 consecutive bins
  // = 8 cache lines otherwise) across 128 distinct lines -> kills L2
  // same-line atomic serialization (19 cyc/atomic measured in R3/R4).
  if (valid) atomicAdd(&hist16[hslot(kk >> 16)], 1u);
}

// ---------------- 2. scan 65536-bin histogram (bit-reversed layout) ----------------
// Stage permuted hist via coalesced uint4 reads, un-permute into 128KB LDS u16
// (max bin count ~1300 << 65535), then scan from LDS exactly as before.
__global__ void __launch_bounds__(1024) k_scan16(const uint32_t* __restrict__ hist16,
                                                 int* __restrict__ scal) {
  __shared__ unsigned short hh[65536];   // 128 KB
  __shared__ uint32_t part[1024];
  int t = threadIdx.x;
  const uint4* h4 = (const uint4*)hist16;
#pragma unroll
  for (int k = 0; k < 16; k++) {
    uint4 v = h4[k * 1024 + t];
    uint32_t base = 4 * (k * 1024 + t);   // permuted-space index
    hh[__brev(base + 0) >> 16] = (unsigned short)v.x;  // brev is an involution:
    hh[__brev(base + 1) >> 16] = (unsigned short)v.y;  // un-permute back to bin order
    hh[__brev(base + 2) >> 16] = (unsigned short)v.z;
    hh[__brev(base + 3) >> 16] = (unsigned short)v.w;
  }
  __syncthreads();
  uint32_t sum = 0;
  for (int b = 0; b < 64; b++) sum += hh[t * 64 + b];
  part[t] = sum;
  __syncthreads();
  for (int off = 1; off < 1024; off <<= 1) {
    uint32_t v = (t >= off) ? part[t - off] : 0;
    __syncthreads();
    part[t] += v;
    __syncthreads();
  }
  uint32_t excl = part[t] - sum;
  if (excl < TOPK && excl + sum >= TOPK) {
    uint32_t cum = excl;
    for (int b = 0; b < 64; b++) {
      uint32_t h = hh[t * 64 + b];
      if (cum < TOPK && cum + h >= TOPK) { scal[0] = t * 64 + b; scal[1] = (int)cum; break; }
      cum += h;
    }
  }
}

// ---------------- 3. 8-bit refinement histogram ----------------
__global__ void k_hist8(const uint32_t* __restrict__ key, const int* __restrict__ scal,
                        uint32_t* __restrict__ hist8) {
  int i = blockIdx.x * blockDim.x + threadIdx.x;
  if (i >= NN) return;
  uint32_t P = (uint32_t)scal[0];
  uint32_t kk = key[i];
  if ((kk >> 16) == P) atomicAdd(&hist8[(kk >> 8) & 0xFFu], 1u);
}

__global__ void __launch_bounds__(256) k_scan8(const uint32_t* __restrict__ hist8,
                                               int* __restrict__ scal) {
  __shared__ uint32_t part[256];
  int t = threadIdx.x;
  uint32_t h = hist8[t];
  part[t] = h;
  __syncthreads();
  for (int off = 1; off < 256; off <<= 1) {
    uint32_t v = (t >= off) ? part[t - off] : 0;
    __syncthreads();
    part[t] += v;
    __syncthreads();
  }
  uint32_t excl = part[t] - h;
  uint32_t cb = (uint32_t)scal[1];
  if (cb + excl < TOPK && cb + excl + h >= TOPK)
    scal[2] = (scal[0] << 8) | t;
}

// ---------------- 4. compact candidates (prefix24 <= T24) ----------------
__global__ void k_compact(const uint32_t* __restrict__ key, int* __restrict__ scal,
                          unsigned long long* __restrict__ sortbuf) {
  __shared__ int lcnt, lbase;
  int t = threadIdx.x;
  int i = blockIdx.x * blockDim.x + t;
  if (t == 0) lcnt = 0;
  __syncthreads();
  bool sel = false;
  uint32_t kk = 0;
  int my = 0;
  if (i < NN) {
    uint32_t T24 = (uint32_t)scal[2];
    kk = key[i];
    if ((kk >> 8) <= T24) { sel = true; my = atomicAdd(&lcnt, 1); }
  }
  __syncthreads();
  if (t == 0 && lcnt > 0) lbase = atomicAdd(&scal[3], lcnt);
  __syncthreads();
  if (sel) {
    int pos = lbase + my;
    if (pos < SORTN) sortbuf[pos] = (((unsigned long long)kk) << 32) | (uint32_t)i;
  }
}

// ---------------- 5. bitonic sort 8192 u64 in LDS + gather top-6000 boxes ----------------
__global__ void __launch_bounds__(1024) k_sort(const unsigned long long* __restrict__ sortbuf,
                                               const float4* __restrict__ roi,
                                               float4* __restrict__ selbox,
                                               uint32_t* __restrict__ selkey) {
  __shared__ unsigned long long sm[SORTN];
  int t = threadIdx.x;
  for (int i = t; i < SORTN; i += 1024) sm[i] = sortbuf[i];
  __syncthreads();
  for (int k = 2; k <= SORTN; k <<= 1) {
    for (int j = k >> 1; j > 0; j >>= 1) {
      for (int p = t; p < SORTN / 2; p += 1024) {
        int i1 = ((p & ~(j - 1)) << 1) | (p & (j - 1));
        int i2 = i1 | j;
        bool up = ((i1 & k) == 0);
        unsigned long long a = sm[i1], b = sm[i2];
        if ((a > b) == up) { sm[i1] = b; sm[i2] = a; }
      }
      __syncthreads();
    }
  }
  for (int r = t; r < KPAD; r += 1024) {
    if (r < (int)TOPK) {
      unsigned long long e = sm[r];
      uint32_t idx = (uint32_t)e;
      selkey[r] = (uint32_t)(e >> 32);
      selbox[r] = roi[idx];
    } else {
      selkey[r] = NEGINF_KEY;
      selbox[r] = make_float4(0.f, 0.f, 0.f, 0.f);
    }
  }
}

// ---------------- 6. suppression bitmask matrix ----------------
__global__ void __launch_bounds__(64) k_mask(const float4* __restrict__ selbox,
                                             unsigned long long* __restrict__ mask) {
  int bi = blockIdx.x, bj = blockIdx.y;
  if (bj < bi) return;
  int t = threadIdx.x;
  __shared__ float4 jb[64];
  __shared__ float  ja[64];
  int j0 = bj * 64;
  float4 cb = selbox[j0 + t];
  jb[t] = cb;
  ja[t] = (cb.z - cb.x) * (cb.w - cb.y);
  __syncthreads();
  int i = bi * 64 + t;
  unsigned long long word = 0;
  if (i < (int)TOPK) {
    float4 bi4 = selbox[i];
    float ai = (bi4.z - bi4.x) * (bi4.w - bi4.y);
    for (int jj = 0; jj < 64; jj++) {
      int j = j0 + jj;
      float4 bb = jb[jj];
      float ltx = fmaxf(bi4.x, bb.x), lty = fmaxf(bi4.y, bb.y);
      float rbx = fminf(bi4.z, bb.z), rby = fminf(bi4.w, bb.w);
      float wx = fmaxf(rbx - ltx, 0.0f), wy = fmaxf(rby - lty, 0.0f);
      float inter = wx * wy;
      float iou = inter / (ai + ja[jj] - inter + 1e-9f);
      if (iou > 0.7f && j > i && j < (int)TOPK) word |= (1ull << jj);
    }
  }
  mask[(size_t)i * KW + bj] = word;
}

// ---------------- 7. sequential greedy keep + output ----------------
__global__ void __launch_bounds__(512) k_seq(const unsigned long long* __restrict__ mask,
                                             const uint32_t* __restrict__ selkey,
                                             const float4* __restrict__ selbox,
                                             float* __restrict__ out) {
  __shared__ unsigned long long smb[2][64][KW];   // 96256 B, double-buffered chunk rows
  __shared__ unsigned long long keepw[KW];
  __shared__ uint32_t wrank[KW];
  __shared__ uint32_t rowflag[2][64];             // row has nonzero word > chunk
  const int t = threadIdx.x;
  const int lane = t & 63;

  // static per-thread staging map: 64 rows x 47 ulonglong2 = 3008 chunks, 6 iters
  int offs[6], w0[6], rr[6];
#pragma unroll
  for (int it = 0; it < 6; it++) {
    int idx = it * 512 + t;
    int r = idx / 47, c2 = idx - r * 47;
    offs[it] = r * (KW * 8) + c2 * 16;
    w0[it] = 2 * c2;
    rr[it] = r;
  }
  ulonglong2 VA[6], VB[6];

#define STAGE_LOAD(cn, V)                                                     \
  if ((cn) < KW) {                                                            \
    const char* mb_ = (const char*)mask + (size_t)(cn) * (64 * KW * 8);       \
    _Pragma("unroll")                                                         \
    for (int it = 0; it < 6; it++)                                            \
      if (it < 5 || t < 448) V[it] = *(const ulonglong2*)(mb_ + offs[it]);    \
  }

#define STAGE_WRITE(cn, V, p)                                                 \
  if ((cn) < KW) {                                                            \
    char* sb_ = (char*)&smb[p][0][0];                                         \
    _Pragma("unroll")                                                         \
    for (int it = 0; it < 6; it++)                                            \
      if (it < 5 || t < 448) {                                                \
        *(ulonglong2*)(sb_ + offs[it]) = V[it];                               \
        unsigned long long nz =                                               \
            (w0[it] > (cn)) ? (V[it].x | V[it].y)                             \
                            : ((w0[it] + 1 > (cn)) ? V[it].y : 0ull);         \
        if (nz) atomicOr(&rowflag[p][rr[it]], 1u);                            \
      }                                                                       \
  }

  // ---- prologue: chunk 0 and 1 in flight; chunk 0 written ----
  STAGE_LOAD(0, VA)
  STAGE_LOAD(1, VB)
  if (t < 64) { rowflag[0][t] = 0; rowflag[1][t] = 0; }
  if (t < KW) {
    unsigned long long w = 0;
    for (int b = 0; b < 64; b++) {
      int r = t * 64 + b;
      if (r < (int)TOPK && selkey[r] != NEGINF_KEY) w |= (1ull << b);
    }
    keepw[t] = w;
  }
  __syncthreads();               // rowflag zero visible before STAGE_WRITE's atomicOr
  STAGE_WRITE(0, VA, 0)          // vmcnt auto-wait on VA only
  __syncthreads();

#define CHUNK_BODY(c, VL, VW)                                                 \
  {                                                                           \
    const int pc = (c) & 1, qn = ((c) + 1) & 1;                               \
    STAGE_LOAD((c) + 2, VL)                                                   \
    if (t < 64) rowflag[qn][t] = 0;                                           \
    if (t < 64) {                                                             \
      unsigned long long mb = smb[pc][lane][(c)];                             \
      unsigned long long w = keepw[(c)];                                      \
      unsigned long long sup = __ballot(mb != 0);                             \
      unsigned long long rem = w & sup;                                       \
      while (rem) {                                                           \
        int b = (int)__builtin_ctzll(rem);                                    \
        unsigned long long mlo = __builtin_amdgcn_readlane((uint32_t)mb, b);  \
        unsigned long long mhi =                                              \
            __builtin_amdgcn_readlane((uint32_t)(mb >> 32), b);               \
        w &= ~((mhi << 32) | mlo);                                            \
        rem = (b >= 63) ? 0ull : (w & sup & (~0ull << (b + 1)));              \
      }                                                                       \
      if (lane == 0) keepw[(c)] = w;                                          \
    }                                                                         \
    __syncthreads();                                                          \
    {                                                                         \
      uint32_t rfv = rowflag[pc][lane];                                       \
      unsigned long long ra = __ballot(rfv != 0);                             \
      unsigned long long w2 = keepw[(c)] & ra;                                \
      int idx = (c) + 1 + t;                                                  \
      if (idx < KW) {                                                         \
        unsigned long long acc = 0, rem2 = w2;                                \
        while (rem2) {                                                        \
          int b = (int)__builtin_ctzll(rem2);                                 \
          rem2 &= rem2 - 1;                                                   \
          acc |= smb[pc][b][idx];                                             \
        }                                                                     \
        keepw[idx] &= ~acc;                                                   \
      }                                                                       \
    }                                                                         \
    STAGE_WRITE((c) + 1, VW, qn)                                              \
    __syncthreads();                                                          \
  }

  for (int c = 0; c < KW; c += 2) {
    CHUNK_BODY(c, VA, VB)        // even: load c+2 -> VA, write c+1 from VB
    CHUNK_BODY(c + 1, VB, VA)    // odd:  load c+3 -> VB, write c+2 from VA
  }
#undef CHUNK_BODY
#undef STAGE_LOAD
#undef STAGE_WRITE

  // ranks of kept rows
  if (t == 0) {
    uint32_t cum = 0;
    for (int w = 0; w < KW; w++) { wrank[w] = cum; cum += (uint32_t)__popcll(keepw[w]); }
  }
  __syncthreads();
  for (int o = t; o < OUTK * 4; o += 512) out[o] = 0.0f;
  __syncthreads();
  for (int r = t; r < (int)TOPK; r += 512) {
    unsigned long long w = keepw[r >> 6];
    int b = r & 63;
    if ((w >> b) & 1ull) {
      uint32_t rank = wrank[r >> 6] + (uint32_t)__popcll(w & ((1ull << b) - 1ull));
      if (rank < OUTK) {
        float4 bx = selbox[r];
        out[rank * 4 + 0] = bx.x;
        out[rank * 4 + 1] = bx.y;
        out[rank * 4 + 2] = bx.z;
        out[rank * 4 + 3] = bx.w;
      }
    }
  }
}

// ---------------- launch ----------------
extern "C" void kernel_launch(void* const* d_in, const int* in_sizes, int n_in,
                              void* d_out, int out_size, void* d_ws, size_t ws_size,
                              hipStream_t stream) {
  const float* cls    = (const float*)d_in[0];
  const float* reg    = (const float*)d_in[1];
  const float* anchor = (const float*)d_in[2];
  float* out = (float*)d_out;
  char* ws = (char*)d_ws;

  float4*   roi     = (float4*)(ws + OFF_ROI);
  uint32_t* key     = (uint32_t*)(ws + OFF_KEY);
  uint32_t* hist16  = (uint32_t*)(ws + OFF_HIST16);
  uint32_t* hist8   = (uint32_t*)(ws + OFF_HIST8);
  int*      scal    = (int*)(ws + OFF_SCAL);
  unsigned long long* sortbuf = (unsigned long long*)(ws + OFF_SORT);
  float4*   selbox  = (float4*)(ws + OFF_SELBOX);
  uint32_t* selkey  = (uint32_t*)(ws + OFF_SELKEY);
  unsigned long long* mask = (unsigned long long*)(ws + OFF_MASK);

  hipMemsetAsync(ws + OFF_HIST16, 0, ZERO_BYTES, stream);
  hipMemsetAsync(ws + OFF_SORT, 0xFF, (size_t)SORTN * 8, stream);

  int blocks = (NN + 255) / 256;
  k_decode<<<blocks, 256, 0, stream>>>(cls, reg, anchor, roi, key, hist16);
  k_scan16<<<1, 1024, 0, stream>>>(hist16, scal);
  k_hist8<<<blocks, 256, 0, stream>>>(key, scal, hist8);
  k_scan8<<<1, 256, 0, stream>>>(hist8, scal);
  k_compact<<<blocks, 256, 0, stream>>>(key, scal, sortbuf);
  k_sort<<<1, 1024, 0, stream>>>(sortbuf, roi, selbox, selkey);
  k_mask<<<dim3(KW, KW), 64, 0, stream>>>(selbox, mask);
  k_seq<<<1, 512, 0, stream>>>(mask, selkey, selbox, out);
}

// Round 6
// 220.958 us; speedup vs baseline: 8.5254x; 1.3889x over previous
//
#include <hip/hip_runtime.h>
#include <stdint.h>

#pragma clang fp contract(off)

#define NN    300000
#define TOPK  6000u
#define KW    94
#define KPAD  6016
#define SORTN 8192
#define OUTK  300
#define ECAP  8192
#define NEGINF_KEY 0xFF800000u

// ---------------- workspace layout (bytes) ----------------
static constexpr size_t OFF_ROI    = 0;                                   // NN*16
static constexpr size_t OFF_KEY    = OFF_ROI + (size_t)NN * 16;           // NN*4
static constexpr size_t OFF_HIST16 = ((OFF_KEY + (size_t)NN * 4 + 255) & ~(size_t)255); // 65536*4
static constexpr size_t OFF_HIST8  = OFF_HIST16 + 65536 * 4;              // 256*4
static constexpr size_t OFF_SCAL   = OFF_HIST8 + 256 * 4;                 // 256 B scalars
static constexpr size_t OFF_ECNT   = OFF_SCAL + 256;                      // 94*4, pad 512
static constexpr size_t ZERO_BYTES = (OFF_ECNT + 512) - OFF_HIST16;
static constexpr size_t OFF_SORT   = OFF_ECNT + 512;                      // SORTN*8
static constexpr size_t OFF_SELBOX = OFF_SORT + (size_t)SORTN * 8;        // KPAD*16
static constexpr size_t OFF_SELKEY = OFF_SELBOX + (size_t)KPAD * 16;      // KPAD*4
static constexpr size_t OFF_DIAG   = ((OFF_SELKEY + (size_t)KPAD * 4 + 255) & ~(size_t)255); // KPAD*8
static constexpr size_t OFF_ELIST  = OFF_DIAG + (size_t)KPAD * 8;         // KW*ECAP*4 ~= 3.0 MB
// total ~ 9.6 MB

// scal[] layout: [0]=P16 bin, [1]=count_below16, [2]=T24 prefix, [3]=compact counter

__device__ __forceinline__ uint32_t score_key(float s) {
  uint32_t u = __float_as_uint(s);
  u = (u >> 31) ? ~u : (u | 0x80000000u);  // monotonic: ascending uint == ascending float
  return ~u;                               // invert: ascending uint == DESCENDING float
}

// bit-reversed histogram slot: consecutive bins -> distinct cache lines.
__device__ __forceinline__ uint32_t hslot(uint32_t b) { return __brev(b) >> 16; }

// ---------------- 1. decode + key + 16-bit histogram ----------------
__global__ void k_decode(const float* __restrict__ cls, const float* __restrict__ reg,
                         const float* __restrict__ anchor, float4* __restrict__ roi,
                         uint32_t* __restrict__ key, uint32_t* __restrict__ hist16) {
  int i = blockIdx.x * blockDim.x + threadIdx.x;
  if (i >= NN) return;
  // softmax(cls)[1], bit-identical op sequence; exp(0)==1.0 exactly -> one f64 exp
  float c0 = cls[2 * i], c1 = cls[2 * i + 1];
  float m  = fmaxf(c0, c1);
  float a0 = c0 - m, a1 = c1 - m;          // one is exactly 0.0f
  float tn = fminf(a0, a1);
  float e  = (float)exp((double)tn);
  float e0 = (a0 == 0.0f) ? 1.0f : e;
  float e1 = (a1 == 0.0f) ? 1.0f : e;
  float s  = e1 / (e0 + e1);

  float4 a = ((const float4*)anchor)[i];
  float acx = (a.x + a.z) * 0.5f;
  float acy = (a.y + a.w) * 0.5f;
  float aw  = a.z - a.x;
  float ah  = a.w - a.y;
  float4 r = ((const float4*)reg)[i];
  float cx = r.x * aw + acx;
  float cy = r.y * ah + acy;
  float w  = (float)exp((double)r.z) * aw;
  float h  = (float)exp((double)r.w) * ah;
  float x1 = cx - w * 0.5f, y1 = cy - h * 0.5f;
  float x2 = cx + w * 0.5f, y2 = cy + h * 0.5f;
  x1 = fminf(fmaxf(x1, 0.0f), 1.0f);
  y1 = fminf(fmaxf(y1, 0.0f), 1.0f);
  x2 = fminf(fmaxf(x2, 0.0f), 1.0f);
  y2 = fminf(fmaxf(y2, 0.0f), 1.0f);
  float ws_ = x2 - x1, hs_ = y2 - y1;
  bool valid = (hs_ >= 0.001f) && (ws_ >= 0.001f);
  float msc = valid ? s : -__builtin_inff();
  uint32_t kk = score_key(msc);

  roi[i] = make_float4(x1, y1, x2, y2);
  key[i] = kk;
  if (valid) atomicAdd(&hist16[hslot(kk >> 16)], 1u);
}

// ---------------- 2. scan 65536-bin histogram (bit-reversed layout) ----------------
__global__ void __launch_bounds__(1024) k_scan16(const uint32_t* __restrict__ hist16,
                                                 int* __restrict__ scal) {
  __shared__ unsigned short hh[65536];   // 128 KB
  __shared__ uint32_t part[1024];
  int t = threadIdx.x;
  const uint4* h4 = (const uint4*)hist16;
#pragma unroll
  for (int k = 0; k < 16; k++) {
    uint4 v = h4[k * 1024 + t];
    uint32_t base = 4 * (k * 1024 + t);   // permuted-space index
    hh[__brev(base + 0) >> 16] = (unsigned short)v.x;  // brev is an involution
    hh[__brev(base + 1) >> 16] = (unsigned short)v.y;
    hh[__brev(base + 2) >> 16] = (unsigned short)v.z;
    hh[__brev(base + 3) >> 16] = (unsigned short)v.w;
  }
  __syncthreads();
  uint32_t sum = 0;
  for (int b = 0; b < 64; b++) sum += hh[t * 64 + b];
  part[t] = sum;
  __syncthreads();
  for (int off = 1; off < 1024; off <<= 1) {
    uint32_t v = (t >= off) ? part[t - off] : 0;
    __syncthreads();
    part[t] += v;
    __syncthreads();
  }
  uint32_t excl = part[t] - sum;
  if (excl < TOPK && excl + sum >= TOPK) {
    uint32_t cum = excl;
    for (int b = 0; b < 64; b++) {
      uint32_t h = hh[t * 64 + b];
      if (cum < TOPK && cum + h >= TOPK) { scal[0] = t * 64 + b; scal[1] = (int)cum; break; }
      cum += h;
    }
  }
}

// ---------------- 3. 8-bit refinement histogram ----------------
__global__ void k_hist8(const uint32_t* __restrict__ key, const int* __restrict__ scal,
                        uint32_t* __restrict__ hist8) {
  int i = blockIdx.x * blockDim.x + threadIdx.x;
  if (i >= NN) return;
  uint32_t P = (uint32_t)scal[0];
  uint32_t kk = key[i];
  if ((kk >> 16) == P) atomicAdd(&hist8[(kk >> 8) & 0xFFu], 1u);
}

__global__ void __launch_bounds__(256) k_scan8(const uint32_t* __restrict__ hist8,
                                               int* __restrict__ scal) {
  __shared__ uint32_t part[256];
  int t = threadIdx.x;
  uint32_t h = hist8[t];
  part[t] = h;
  __syncthreads();
  for (int off = 1; off < 256; off <<= 1) {
    uint32_t v = (t >= off) ? part[t - off] : 0;
    __syncthreads();
    part[t] += v;
    __syncthreads();
  }
  uint32_t excl = part[t] - h;
  uint32_t cb = (uint32_t)scal[1];
  if (cb + excl < TOPK && cb + excl + h >= TOPK)
    scal[2] = (scal[0] << 8) | t;
}

// ---------------- 4. compact candidates (prefix24 <= T24) ----------------
__global__ void k_compact(const uint32_t* __restrict__ key, int* __restrict__ scal,
                          unsigned long long* __restrict__ sortbuf) {
  __shared__ int lcnt, lbase;
  int t = threadIdx.x;
  int i = blockIdx.x * blockDim.x + t;
  if (t == 0) lcnt = 0;
  __syncthreads();
  bool sel = false;
  uint32_t kk = 0;
  int my = 0;
  if (i < NN) {
    uint32_t T24 = (uint32_t)scal[2];
    kk = key[i];
    if ((kk >> 8) <= T24) { sel = true; my = atomicAdd(&lcnt, 1); }
  }
  __syncthreads();
  if (t == 0 && lcnt > 0) lbase = atomicAdd(&scal[3], lcnt);
  __syncthreads();
  if (sel) {
    int pos = lbase + my;
    if (pos < SORTN) sortbuf[pos] = (((unsigned long long)kk) << 32) | (uint32_t)i;
  }
}

// ---------------- 5. bitonic sort 8192 u64 in LDS + gather top-6000 boxes ----------------
__global__ void __launch_bounds__(1024) k_sort(const unsigned long long* __restrict__ sortbuf,
                                               const float4* __restrict__ roi,
                                               float4* __restrict__ selbox,
                                               uint32_t* __restrict__ selkey) {
  __shared__ unsigned long long sm[SORTN];
  int t = threadIdx.x;
  for (int i = t; i < SORTN; i += 1024) sm[i] = sortbuf[i];
  __syncthreads();
  for (int k = 2; k <= SORTN; k <<= 1) {
    for (int j = k >> 1; j > 0; j >>= 1) {
      for (int p = t; p < SORTN / 2; p += 1024) {
        int i1 = ((p & ~(j - 1)) << 1) | (p & (j - 1));
        int i2 = i1 | j;
        bool up = ((i1 & k) == 0);
        unsigned long long a = sm[i1], b = sm[i2];
        if ((a > b) == up) { sm[i1] = b; sm[i2] = a; }
      }
      __syncthreads();
    }
  }
  for (int r = t; r < KPAD; r += 1024) {
    if (r < (int)TOPK) {
      unsigned long long e = sm[r];
      uint32_t idx = (uint32_t)e;
      selkey[r] = (uint32_t)(e >> 32);
      selbox[r] = roi[idx];
    } else {
      selkey[r] = NEGINF_KEY;
      selbox[r] = make_float4(0.f, 0.f, 0.f, 0.f);
    }
  }
}

// ---------------- 6. suppression: dense diagonal blocks + sparse inter-chunk entries ----
// diag[i]     : 64-bit word, bits jj>i_local within i's own chunk that i suppresses
// elist[bi][] : packed (i_local<<16 | j) for inter-chunk suppressions (bj > bi)
__global__ void __launch_bounds__(64) k_mask(const float4* __restrict__ selbox,
                                             unsigned long long* __restrict__ diag,
                                             uint32_t* __restrict__ ecnt,
                                             uint32_t* __restrict__ elist) {
  int bi = blockIdx.x, bj = blockIdx.y;
  if (bj < bi) return;
  int t = threadIdx.x;
  __shared__ float4 jb[64];
  __shared__ float  ja[64];
  int j0 = bj * 64;
  float4 cb = selbox[j0 + t];
  jb[t] = cb;
  ja[t] = (cb.z - cb.x) * (cb.w - cb.y);
  __syncthreads();
  int i = bi * 64 + t;
  unsigned long long word = 0;
  if (i < (int)TOPK) {
    float4 bi4 = selbox[i];
    float ai = (bi4.z - bi4.x) * (bi4.w - bi4.y);
    for (int jj = 0; jj < 64; jj++) {
      int j = j0 + jj;
      float4 bb = jb[jj];
      float ltx = fmaxf(bi4.x, bb.x), lty = fmaxf(bi4.y, bb.y);
      float rbx = fminf(bi4.z, bb.z), rby = fminf(bi4.w, bb.w);
      float wx = fmaxf(rbx - ltx, 0.0f), wy = fmaxf(rby - lty, 0.0f);
      float inter = wx * wy;
      float iou = inter / (ai + ja[jj] - inter + 1e-9f);
      if (iou > 0.7f && j > i && j < (int)TOPK) word |= (1ull << jj);
    }
  }
  if (bi == bj) {
    diag[i] = word;                       // dense diagonal (needed by serial resolve)
    return;
  }
  // sparse append: wave-prefix over per-thread popcounts, one atomic per block
  uint32_t cnt = (uint32_t)__popcll(word);
  uint32_t pre = cnt;
#pragma unroll
  for (int off = 1; off < 64; off <<= 1) {
    uint32_t v = __shfl_up(pre, off);
    if (t >= off) pre += v;
  }
  uint32_t total = __shfl(pre, 63);
  if (total == 0) return;                 // wave-uniform
  uint32_t excl = pre - cnt;
  uint32_t base;
  if (t == 0) base = atomicAdd(&ecnt[bi], total);
  base = __shfl(base, 0);
  unsigned long long rem = word;
  uint32_t k = 0;
  while (rem) {
    int jj = (int)__builtin_ctzll(rem);
    rem &= rem - 1;
    uint32_t pos = base + excl + k;
    k++;
    if (pos < ECAP) elist[(size_t)bi * ECAP + pos] = ((uint32_t)t << 16) | (uint32_t)(j0 + jj);
  }
}

// ---------------- 7. sequential greedy keep + output (sparse) ----------------
// Per chunk c: phase1 = wave-0 serial intra-chunk resolve from prefetched diag
// regs; phase2 = parallel atomicAnd of the chunk's sparse entry list into the
// LDS keep bitmap. Diag+entry regs prefetched 2 chunks ahead (T14).
__global__ void __launch_bounds__(256) k_seq(const unsigned long long* __restrict__ diag,
                                             const uint32_t* __restrict__ ecnt,
                                             const uint32_t* __restrict__ elist,
                                             const uint32_t* __restrict__ selkey,
                                             const float4* __restrict__ selbox,
                                             float* __restrict__ out) {
  __shared__ uint32_t keep32[2 * KW];
  __shared__ uint32_t wrank[KW];
  __shared__ int scnt[KW];
  const int t = threadIdx.x;
  const int lane = t & 63;

  if (t < 2 * KW) {
    uint32_t w = 0;
    for (int b = 0; b < 32; b++) {
      int r = t * 32 + b;
      if (r < (int)TOPK && selkey[r] != NEGINF_KEY) w |= (1u << b);
    }
    keep32[t] = w;
  }
  if (t < KW) {
    int c0 = (int)ecnt[t];
    scnt[t] = (c0 > ECAP) ? ECAP : c0;
  }
  // depth-2 register prefetch (static reg sets, bodies unrolled x2 per rule #20)
  unsigned long long D0 = (t < 64) ? diag[t] : 0ull;
  uint32_t E0 = elist[t];
  unsigned long long D1 = (t < 64) ? diag[64 + t] : 0ull;
  uint32_t E1 = elist[ECAP + t];
  __syncthreads();

#define CHUNK_BODY(c, DD, EE)                                                 \
  {                                                                           \
    unsigned long long mb = DD;                                               \
    uint32_t ee = EE;                                                         \
    if ((c) + 2 < KW) {                                                       \
      DD = (t < 64) ? diag[((c) + 2) * 64 + t] : 0ull;                        \
      EE = elist[(size_t)((c) + 2) * ECAP + t];                               \
    }                                                                         \
    if (t < 64) {                                                             \
      unsigned long long w =                                                  \
          ((unsigned long long)keep32[2 * (c) + 1] << 32) | keep32[2 * (c)];  \
      unsigned long long sup = __ballot(mb != 0);                             \
      unsigned long long rem = w & sup;                                       \
      while (rem) {                                                           \
        int b = (int)__builtin_ctzll(rem);                                    \
        unsigned long long mlo = __builtin_amdgcn_readlane((uint32_t)mb, b);  \
        unsigned long long mhi =                                              \
            __builtin_amdgcn_readlane((uint32_t)(mb >> 32), b);               \
        w &= ~((mhi << 32) | mlo);                                            \
        rem = (b >= 63) ? 0ull : (w & sup & (~0ull << (b + 1)));              \
      }                                                                       \
      if (lane == 0) {                                                        \
        keep32[2 * (c)] = (uint32_t)w;                                        \
        keep32[2 * (c) + 1] = (uint32_t)(w >> 32);                            \
      }                                                                       \
    }                                                                         \
    __syncthreads();                                                          \
    {                                                                         \
      int cn = scnt[(c)];                                                     \
      unsigned long long wc =                                                 \
          ((unsigned long long)keep32[2 * (c) + 1] << 32) | keep32[2 * (c)];  \
      for (int k = t; k < cn; k += 256) {                                     \
        uint32_t e = (k == t) ? ee : elist[(size_t)(c)*ECAP + k];             \
        int il = (int)(e >> 16), j = (int)(e & 0xFFFFu);                      \
        if ((wc >> il) & 1ull)                                                \
          atomicAnd(&keep32[j >> 5], ~(1u << (j & 31)));                      \
      }                                                                       \
    }                                                                         \
    __syncthreads();                                                          \
  }

  for (int c = 0; c < KW; c += 2) {
    CHUNK_BODY(c, D0, E0)
    CHUNK_BODY(c + 1, D1, E1)
  }
#undef CHUNK_BODY

  // ranks of kept rows
  if (t == 0) {
    uint32_t cum = 0;
    for (int w = 0; w < KW; w++) {
      wrank[w] = cum;
      cum += (uint32_t)(__popc(keep32[2 * w]) + __popc(keep32[2 * w + 1]));
    }
  }
  __syncthreads();
  for (int o = t; o < OUTK * 4; o += 256) out[o] = 0.0f;
  __syncthreads();
  for (int r = t; r < (int)TOPK; r += 256) {
    unsigned long long w =
        ((unsigned long long)keep32[2 * (r >> 6) + 1] << 32) | keep32[2 * (r >> 6)];
    int b = r & 63;
    if ((w >> b) & 1ull) {
      uint32_t rank = wrank[r >> 6] + (uint32_t)__popcll(w & ((1ull << b) - 1ull));
      if (rank < OUTK) {
        float4 bx = selbox[r];
        out[rank * 4 + 0] = bx.x;
        out[rank * 4 + 1] = bx.y;
        out[rank * 4 + 2] = bx.z;
        out[rank * 4 + 3] = bx.w;
      }
    }
  }
}

// ---------------- launch ----------------
extern "C" void kernel_launch(void* const* d_in, const int* in_sizes, int n_in,
                              void* d_out, int out_size, void* d_ws, size_t ws_size,
                              hipStream_t stream) {
  const float* cls    = (const float*)d_in[0];
  const float* reg    = (const float*)d_in[1];
  const float* anchor = (const float*)d_in[2];
  float* out = (float*)d_out;
  char* ws = (char*)d_ws;

  float4*   roi     = (float4*)(ws + OFF_ROI);
  uint32_t* key     = (uint32_t*)(ws + OFF_KEY);
  uint32_t* hist16  = (uint32_t*)(ws + OFF_HIST16);
  uint32_t* hist8   = (uint32_t*)(ws + OFF_HIST8);
  int*      scal    = (int*)(ws + OFF_SCAL);
  uint32_t* ecnt    = (uint32_t*)(ws + OFF_ECNT);
  unsigned long long* sortbuf = (unsigned long long*)(ws + OFF_SORT);
  float4*   selbox  = (float4*)(ws + OFF_SELBOX);
  uint32_t* selkey  = (uint32_t*)(ws + OFF_SELKEY);
  unsigned long long* diag = (unsigned long long*)(ws + OFF_DIAG);
  uint32_t* elist   = (uint32_t*)(ws + OFF_ELIST);

  hipMemsetAsync(ws + OFF_HIST16, 0, ZERO_BYTES, stream);
  hipMemsetAsync(ws + OFF_SORT, 0xFF, (size_t)SORTN * 8, stream);

  int blocks = (NN + 255) / 256;
  k_decode<<<blocks, 256, 0, stream>>>(cls, reg, anchor, roi, key, hist16);
  k_scan16<<<1, 1024, 0, stream>>>(hist16, scal);
  k_hist8<<<blocks, 256, 0, stream>>>(key, scal, hist8);
  k_scan8<<<1, 256, 0, stream>>>(hist8, scal);
  k_compact<<<blocks, 256, 0, stream>>>(key, scal, sortbuf);
  k_sort<<<1, 1024, 0, stream>>>(sortbuf, roi, selbox, selkey);
  k_mask<<<dim3(KW, KW), 64, 0, stream>>>(selbox, diag, ecnt, elist);
  k_seq<<<1, 256, 0, stream>>>(diag, ecnt, elist, selkey, selbox, out);
}

// Round 7
// 177.729 us; speedup vs baseline: 10.5991x; 1.2432x over previous
//
#include <hip/hip_runtime.h>
#include <stdint.h>

#pragma clang fp contract(off)

#define NN    300000
#define TOPK  6000u
#define KW    94
#define KPAD  6016
#define SORTN 8192
#define NCHUNK 16
#define CSZ   512
#define OUTK  300
#define ECAP  8192
#define NEGINF_KEY 0xFF800000u

// ---------------- workspace layout (bytes) ----------------
static constexpr size_t OFF_ROI    = 0;                                   // NN*16
static constexpr size_t OFF_KEY    = OFF_ROI + (size_t)NN * 16;           // NN*4
static constexpr size_t OFF_HIST16 = ((OFF_KEY + (size_t)NN * 4 + 255) & ~(size_t)255); // 65536*4
static constexpr size_t OFF_HIST8  = OFF_HIST16 + 65536 * 4;              // 256*4
static constexpr size_t OFF_SCAL   = OFF_HIST8 + 256 * 4;                 // 256 B scalars
static constexpr size_t OFF_ECNT   = OFF_SCAL + 256;                      // 94*4, pad 512
static constexpr size_t ZERO_BYTES = (OFF_ECNT + 512) - OFF_HIST16;
static constexpr size_t OFF_SORT   = OFF_ECNT + 512;                      // SORTN*8
static constexpr size_t OFF_SELBOX = OFF_SORT + (size_t)SORTN * 8;        // KPAD*16
static constexpr size_t OFF_SELKEY = OFF_SELBOX + (size_t)KPAD * 16;      // KPAD*4
static constexpr size_t OFF_DIAG   = ((OFF_SELKEY + (size_t)KPAD * 4 + 255) & ~(size_t)255); // KPAD*8
static constexpr size_t OFF_ELIST  = OFF_DIAG + (size_t)KPAD * 8;         // KW*ECAP*4 ~= 3.0 MB

// scal[] layout: [0]=P16 bin, [1]=count_below16, [2]=T24 prefix, [3]=compact counter

__device__ __forceinline__ uint32_t score_key(float s) {
  uint32_t u = __float_as_uint(s);
  u = (u >> 31) ? ~u : (u | 0x80000000u);  // monotonic: ascending uint == ascending float
  return ~u;                               // invert: ascending uint == DESCENDING float
}

// bit-reversed histogram slot: consecutive bins -> distinct cache lines.
__device__ __forceinline__ uint32_t hslot(uint32_t b) { return __brev(b) >> 16; }

// ---------------- 1. decode + key + 16-bit histogram ----------------
__global__ void k_decode(const float* __restrict__ cls, const float* __restrict__ reg,
                         const float* __restrict__ anchor, float4* __restrict__ roi,
                         uint32_t* __restrict__ key, uint32_t* __restrict__ hist16) {
  int i = blockIdx.x * blockDim.x + threadIdx.x;
  if (i >= NN) return;
  // softmax(cls)[1], bit-identical op sequence; exp(0)==1.0 exactly -> one f64 exp
  float c0 = cls[2 * i], c1 = cls[2 * i + 1];
  float m  = fmaxf(c0, c1);
  float a0 = c0 - m, a1 = c1 - m;          // one is exactly 0.0f
  float tn = fminf(a0, a1);
  float e  = (float)exp((double)tn);
  float e0 = (a0 == 0.0f) ? 1.0f : e;
  float e1 = (a1 == 0.0f) ? 1.0f : e;
  float s  = e1 / (e0 + e1);

  float4 a = ((const float4*)anchor)[i];
  float acx = (a.x + a.z) * 0.5f;
  float acy = (a.y + a.w) * 0.5f;
  float aw  = a.z - a.x;
  float ah  = a.w - a.y;
  float4 r = ((const float4*)reg)[i];
  float cx = r.x * aw + acx;
  float cy = r.y * ah + acy;
  float w  = (float)exp((double)r.z) * aw;
  float h  = (float)exp((double)r.w) * ah;
  float x1 = cx - w * 0.5f, y1 = cy - h * 0.5f;
  float x2 = cx + w * 0.5f, y2 = cy + h * 0.5f;
  x1 = fminf(fmaxf(x1, 0.0f), 1.0f);
  y1 = fminf(fmaxf(y1, 0.0f), 1.0f);
  x2 = fminf(fmaxf(x2, 0.0f), 1.0f);
  y2 = fminf(fmaxf(y2, 0.0f), 1.0f);
  float ws_ = x2 - x1, hs_ = y2 - y1;
  bool valid = (hs_ >= 0.001f) && (ws_ >= 0.001f);
  float msc = valid ? s : -__builtin_inff();
  uint32_t kk = score_key(msc);

  roi[i] = make_float4(x1, y1, x2, y2);
  key[i] = kk;
  if (valid) atomicAdd(&hist16[hslot(kk >> 16)], 1u);
}

// ---------------- 2. scan 65536-bin histogram (bit-reversed layout) ----------------
__global__ void __launch_bounds__(1024) k_scan16(const uint32_t* __restrict__ hist16,
                                                 int* __restrict__ scal) {
  __shared__ unsigned short hh[65536];   // 128 KB
  __shared__ uint32_t part[1024];
  int t = threadIdx.x;
  const uint4* h4 = (const uint4*)hist16;
#pragma unroll
  for (int k = 0; k < 16; k++) {
    uint4 v = h4[k * 1024 + t];
    uint32_t base = 4 * (k * 1024 + t);   // permuted-space index
    hh[__brev(base + 0) >> 16] = (unsigned short)v.x;  // brev is an involution
    hh[__brev(base + 1) >> 16] = (unsigned short)v.y;
    hh[__brev(base + 2) >> 16] = (unsigned short)v.z;
    hh[__brev(base + 3) >> 16] = (unsigned short)v.w;
  }
  __syncthreads();
  uint32_t sum = 0;
  for (int b = 0; b < 64; b++) sum += hh[t * 64 + b];
  part[t] = sum;
  __syncthreads();
  for (int off = 1; off < 1024; off <<= 1) {
    uint32_t v = (t >= off) ? part[t - off] : 0;
    __syncthreads();
    part[t] += v;
    __syncthreads();
  }
  uint32_t excl = part[t] - sum;
  if (excl < TOPK && excl + sum >= TOPK) {
    uint32_t cum = excl;
    for (int b = 0; b < 64; b++) {
      uint32_t h = hh[t * 64 + b];
      if (cum < TOPK && cum + h >= TOPK) { scal[0] = t * 64 + b; scal[1] = (int)cum; break; }
      cum += h;
    }
  }
}

// ---------------- 3. 8-bit refinement histogram ----------------
__global__ void k_hist8(const uint32_t* __restrict__ key, const int* __restrict__ scal,
                        uint32_t* __restrict__ hist8) {
  int i = blockIdx.x * blockDim.x + threadIdx.x;
  if (i >= NN) return;
  uint32_t P = (uint32_t)scal[0];
  uint32_t kk = key[i];
  if ((kk >> 16) == P) atomicAdd(&hist8[(kk >> 8) & 0xFFu], 1u);
}

__global__ void __launch_bounds__(256) k_scan8(const uint32_t* __restrict__ hist8,
                                               int* __restrict__ scal) {
  __shared__ uint32_t part[256];
  int t = threadIdx.x;
  uint32_t h = hist8[t];
  part[t] = h;
  __syncthreads();
  for (int off = 1; off < 256; off <<= 1) {
    uint32_t v = (t >= off) ? part[t - off] : 0;
    __syncthreads();
    part[t] += v;
    __syncthreads();
  }
  uint32_t excl = part[t] - h;
  uint32_t cb = (uint32_t)scal[1];
  if (cb + excl < TOPK && cb + excl + h >= TOPK)
    scal[2] = (scal[0] << 8) | t;
}

// ---------------- 4. compact candidates (prefix24 <= T24) ----------------
__global__ void k_compact(const uint32_t* __restrict__ key, int* __restrict__ scal,
                          unsigned long long* __restrict__ sortbuf) {
  __shared__ int lcnt, lbase;
  int t = threadIdx.x;
  int i = blockIdx.x * blockDim.x + t;
  if (t == 0) lcnt = 0;
  __syncthreads();
  bool sel = false;
  uint32_t kk = 0;
  int my = 0;
  if (i < NN) {
    uint32_t T24 = (uint32_t)scal[2];
    kk = key[i];
    if ((kk >> 8) <= T24) { sel = true; my = atomicAdd(&lcnt, 1); }
  }
  __syncthreads();
  if (t == 0 && lcnt > 0) lbase = atomicAdd(&scal[3], lcnt);
  __syncthreads();
  if (sel) {
    int pos = lbase + my;
    if (pos < SORTN) sortbuf[pos] = (((unsigned long long)kk) << 32) | (uint32_t)i;
  }
}

// ---------------- 5a. per-chunk bitonic sort (16 blocks x 512 elems, in place) --------
__global__ void __launch_bounds__(256) k_sortA(unsigned long long* __restrict__ sortbuf) {
  __shared__ unsigned long long sm[CSZ];
  int t = threadIdx.x;
  unsigned long long* chunk = sortbuf + (size_t)blockIdx.x * CSZ;
  sm[t] = chunk[t];
  sm[t + 256] = chunk[t + 256];
  __syncthreads();
  for (int k = 2; k <= CSZ; k <<= 1) {
    for (int j = k >> 1; j > 0; j >>= 1) {
      int i1 = ((t & ~(j - 1)) << 1) | (t & (j - 1));
      int i2 = i1 | j;
      bool up = ((i1 & k) == 0);
      unsigned long long a = sm[i1], b = sm[i2];
      if ((a > b) == up) { sm[i1] = b; sm[i2] = a; }
      __syncthreads();
    }
  }
  chunk[t] = sm[t];
  chunk[t + 256] = sm[t + 256];
}

// ---------------- 5b. stable multi-merge rank + scatter top-6000 ----------------
// rank(val in chunk c at pos p) = p + sum_{c'<c} count(<= val) + sum_{c'>c} count(< val)
// Ranks are a permutation of 0..SORTN-1 (stable merge), so each output row,
// including the [TOPK,KPAD) padding band, is written exactly once.
__global__ void __launch_bounds__(256) k_sortB(const unsigned long long* __restrict__ sortbuf,
                                               const float4* __restrict__ roi,
                                               float4* __restrict__ selbox,
                                               uint32_t* __restrict__ selkey) {
  int g = blockIdx.x * 256 + threadIdx.x;   // 0..8191
  int c = g >> 9, p = g & (CSZ - 1);        // block-uniform c (512 = 2 blocks/chunk)
  unsigned long long val = sortbuf[g];
  int rank = p;
  for (int c2 = 0; c2 < NCHUNK; c2++) {
    if (c2 == c) continue;
    const unsigned long long* base = sortbuf + ((size_t)c2 << 9);
    bool le = (c2 < c);                     // earlier chunk: count <=, later: count <
    int pos = 0;
#pragma unroll
    for (int s = CSZ; s > 0; s >>= 1) {
      if (pos + s <= CSZ) {
        unsigned long long v = base[pos + s - 1];
        if (le ? (v <= val) : (v < val)) pos += s;
      }
    }
    rank += pos;
  }
  if (rank < (int)TOPK) {
    selkey[rank] = (uint32_t)(val >> 32);
    selbox[rank] = roi[(uint32_t)val];
  } else if (rank < KPAD) {
    selkey[rank] = NEGINF_KEY;
    selbox[rank] = make_float4(0.f, 0.f, 0.f, 0.f);
  }
}

// ---------------- 6. suppression: dense diagonal blocks + sparse inter-chunk entries ----
__global__ void __launch_bounds__(64) k_mask(const float4* __restrict__ selbox,
                                             unsigned long long* __restrict__ diag,
                                             uint32_t* __restrict__ ecnt,
                                             uint32_t* __restrict__ elist) {
  int bi = blockIdx.x, bj = blockIdx.y;
  if (bj < bi) return;
  int t = threadIdx.x;
  __shared__ float4 jb[64];
  __shared__ float  ja[64];
  int j0 = bj * 64;
  float4 cb = selbox[j0 + t];
  jb[t] = cb;
  ja[t] = (cb.z - cb.x) * (cb.w - cb.y);
  __syncthreads();
  int i = bi * 64 + t;
  unsigned long long word = 0;
  if (i < (int)TOPK) {
    float4 bi4 = selbox[i];
    float ai = (bi4.z - bi4.x) * (bi4.w - bi4.y);
    for (int jj = 0; jj < 64; jj++) {
      int j = j0 + jj;
      float4 bb = jb[jj];
      float ltx = fmaxf(bi4.x, bb.x), lty = fmaxf(bi4.y, bb.y);
      float rbx = fminf(bi4.z, bb.z), rby = fminf(bi4.w, bb.w);
      float wx = fmaxf(rbx - ltx, 0.0f), wy = fmaxf(rby - lty, 0.0f);
      float inter = wx * wy;
      float iou = inter / (ai + ja[jj] - inter + 1e-9f);
      if (iou > 0.7f && j > i && j < (int)TOPK) word |= (1ull << jj);
    }
  }
  if (bi == bj) {
    diag[i] = word;                       // dense diagonal (needed by serial resolve)
    return;
  }
  // sparse append: wave-prefix over per-thread popcounts, one atomic per block
  uint32_t cnt = (uint32_t)__popcll(word);
  uint32_t pre = cnt;
#pragma unroll
  for (int off = 1; off < 64; off <<= 1) {
    uint32_t v = __shfl_up(pre, off);
    if (t >= off) pre += v;
  }
  uint32_t total = __shfl(pre, 63);
  if (total == 0) return;                 // wave-uniform
  uint32_t excl = pre - cnt;
  uint32_t base;
  if (t == 0) base = atomicAdd(&ecnt[bi], total);
  base = __shfl(base, 0);
  unsigned long long rem = word;
  uint32_t k = 0;
  while (rem) {
    int jj = (int)__builtin_ctzll(rem);
    rem &= rem - 1;
    uint32_t pos = base + excl + k;
    k++;
    if (pos < ECAP) elist[(size_t)bi * ECAP + pos] = ((uint32_t)t << 16) | (uint32_t)(j0 + jj);
  }
}

// ---------------- 7. sequential greedy keep + output (sparse) ----------------
__global__ void __launch_bounds__(256) k_seq(const unsigned long long* __restrict__ diag,
                                             const uint32_t* __restrict__ ecnt,
                                             const uint32_t* __restrict__ elist,
                                             const uint32_t* __restrict__ selkey,
                                             const float4* __restrict__ selbox,
                                             float* __restrict__ out) {
  __shared__ uint32_t keep32[2 * KW];
  __shared__ uint32_t wrank[KW];
  __shared__ int scnt[KW];
  const int t = threadIdx.x;
  const int lane = t & 63;

  if (t < 2 * KW) {
    uint32_t w = 0;
    for (int b = 0; b < 32; b++) {
      int r = t * 32 + b;
      if (r < (int)TOPK && selkey[r] != NEGINF_KEY) w |= (1u << b);
    }
    keep32[t] = w;
  }
  if (t < KW) {
    int c0 = (int)ecnt[t];
    scnt[t] = (c0 > ECAP) ? ECAP : c0;
  }
  // depth-2 register prefetch (static reg sets, bodies unrolled x2 per rule #20)
  unsigned long long D0 = (t < 64) ? diag[t] : 0ull;
  uint32_t E0 = elist[t];
  unsigned long long D1 = (t < 64) ? diag[64 + t] : 0ull;
  uint32_t E1 = elist[ECAP + t];
  __syncthreads();

#define CHUNK_BODY(c, DD, EE)                                                 \
  {                                                                           \
    unsigned long long mb = DD;                                               \
    uint32_t ee = EE;                                                         \
    if ((c) + 2 < KW) {                                                       \
      DD = (t < 64) ? diag[((c) + 2) * 64 + t] : 0ull;                        \
      EE = elist[(size_t)((c) + 2) * ECAP + t];                               \
    }                                                                         \
    if (t < 64) {                                                             \
      unsigned long long w =                                                  \
          ((unsigned long long)keep32[2 * (c) + 1] << 32) | keep32[2 * (c)];  \
      unsigned long long sup = __ballot(mb != 0);                             \
      unsigned long long rem = w & sup;                                       \
      while (rem) {                                                           \
        int b = (int)__builtin_ctzll(rem);                                    \
        unsigned long long mlo = __builtin_amdgcn_readlane((uint32_t)mb, b);  \
        unsigned long long mhi =                                              \
            __builtin_amdgcn_readlane((uint32_t)(mb >> 32), b);               \
        w &= ~((mhi << 32) | mlo);                                            \
        rem = (b >= 63) ? 0ull : (w & sup & (~0ull << (b + 1)));              \
      }                                                                       \
      if (lane == 0) {                                                        \
        keep32[2 * (c)] = (uint32_t)w;                                        \
        keep32[2 * (c) + 1] = (uint32_t)(w >> 32);                            \
      }                                                                       \
    }                                                                         \
    __syncthreads();                                                          \
    {                                                                         \
      int cn = scnt[(c)];                                                     \
      unsigned long long wc =                                                 \
          ((unsigned long long)keep32[2 * (c) + 1] << 32) | keep32[2 * (c)];  \
      for (int k = t; k < cn; k += 256) {                                     \
        uint32_t e = (k == t) ? ee : elist[(size_t)(c)*ECAP + k];             \
        int il = (int)(e >> 16), j = (int)(e & 0xFFFFu);                      \
        if ((wc >> il) & 1ull)                                                \
          atomicAnd(&keep32[j >> 5], ~(1u << (j & 31)));                      \
      }                                                                       \
    }                                                                         \
    __syncthreads();                                                          \
  }

  for (int c = 0; c < KW; c += 2) {
    CHUNK_BODY(c, D0, E0)
    CHUNK_BODY(c + 1, D1, E1)
  }
#undef CHUNK_BODY

  // ranks of kept rows
  if (t == 0) {
    uint32_t cum = 0;
    for (int w = 0; w < KW; w++) {
      wrank[w] = cum;
      cum += (uint32_t)(__popc(keep32[2 * w]) + __popc(keep32[2 * w + 1]));
    }
  }
  __syncthreads();
  for (int o = t; o < OUTK * 4; o += 256) out[o] = 0.0f;
  __syncthreads();
  for (int r = t; r < (int)TOPK; r += 256) {
    unsigned long long w =
        ((unsigned long long)keep32[2 * (r >> 6) + 1] << 32) | keep32[2 * (r >> 6)];
    int b = r & 63;
    if ((w >> b) & 1ull) {
      uint32_t rank = wrank[r >> 6] + (uint32_t)__popcll(w & ((1ull << b) - 1ull));
      if (rank < OUTK) {
        float4 bx = selbox[r];
        out[rank * 4 + 0] = bx.x;
        out[rank * 4 + 1] = bx.y;
        out[rank * 4 + 2] = bx.z;
        out[rank * 4 + 3] = bx.w;
      }
    }
  }
}

// ---------------- launch ----------------
extern "C" void kernel_launch(void* const* d_in, const int* in_sizes, int n_in,
                              void* d_out, int out_size, void* d_ws, size_t ws_size,
                              hipStream_t stream) {
  const float* cls    = (const float*)d_in[0];
  const float* reg    = (const float*)d_in[1];
  const float* anchor = (const float*)d_in[2];
  float* out = (float*)d_out;
  char* ws = (char*)d_ws;

  float4*   roi     = (float4*)(ws + OFF_ROI);
  uint32_t* key     = (uint32_t*)(ws + OFF_KEY);
  uint32_t* hist16  = (uint32_t*)(ws + OFF_HIST16);
  uint32_t* hist8   = (uint32_t*)(ws + OFF_HIST8);
  int*      scal    = (int*)(ws + OFF_SCAL);
  uint32_t* ecnt    = (uint32_t*)(ws + OFF_ECNT);
  unsigned long long* sortbuf = (unsigned long long*)(ws + OFF_SORT);
  float4*   selbox  = (float4*)(ws + OFF_SELBOX);
  uint32_t* selkey  = (uint32_t*)(ws + OFF_SELKEY);
  unsigned long long* diag = (unsigned long long*)(ws + OFF_DIAG);
  uint32_t* elist   = (uint32_t*)(ws + OFF_ELIST);

  hipMemsetAsync(ws + OFF_HIST16, 0, ZERO_BYTES, stream);
  hipMemsetAsync(ws + OFF_SORT, 0xFF, (size_t)SORTN * 8, stream);

  int blocks = (NN + 255) / 256;
  k_decode<<<blocks, 256, 0, stream>>>(cls, reg, anchor, roi, key, hist16);
  k_scan16<<<1, 1024, 0, stream>>>(hist16, scal);
  k_hist8<<<blocks, 256, 0, stream>>>(key, scal, hist8);
  k_scan8<<<1, 256, 0, stream>>>(hist8, scal);
  k_compact<<<blocks, 256, 0, stream>>>(key, scal, sortbuf);
  k_sortA<<<NCHUNK, 256, 0, stream>>>(sortbuf);
  k_sortB<<<SORTN / 256, 256, 0, stream>>>(sortbuf, roi, selbox, selkey);
  k_mask<<<dim3(KW, KW), 64, 0, stream>>>(selbox, diag, ecnt, elist);
  k_seq<<<1, 256, 0, stream>>>(diag, ecnt, elist, selkey, selbox, out);
}